// Round 3
// baseline (440.154 us; speedup 1.0000x reference)
//
#include <hip/hip_runtime.h>
#include <cstdint>
#include <cstddef>

typedef __attribute__((ext_vector_type(8))) short s8v;
typedef __attribute__((ext_vector_type(4))) float f32x4;

__device__ __forceinline__ unsigned short f2bf(float f) {
  unsigned int u = __builtin_bit_cast(unsigned int, f);
  unsigned int r = (u + 0x7fffu + ((u >> 16) & 1u)) >> 16;
  return (unsigned short)r;
}
__device__ __forceinline__ float bf2f(unsigned short s) {
  unsigned int u = ((unsigned int)s) << 16;
  return __builtin_bit_cast(float, u);
}

__device__ __forceinline__ void gload16(const void* g, void* l) {
  __builtin_amdgcn_global_load_lds(
      (const __attribute__((address_space(1))) void*)g,
      (__attribute__((address_space(3))) void*)l, 16, 0, 0);
}

// ---------------- prep kernels ----------------

__global__ __launch_bounds__(256)
void colsum_kernel(const float* __restrict__ p_mat, const float* __restrict__ r_mat,
                   float* __restrict__ q_vec, float* __restrict__ r_vec) {
  int l = blockIdx.x * 256 + threadIdx.x;   // 0..1023
  float sp = 0.f, sr = 0.f;
  for (int d = 0; d < 1024; ++d) {
    sp += p_mat[d * 1024 + l];
    sr += r_mat[d * 1024 + l];
  }
  q_vec[l] = sp;
  r_vec[l] = sr;
}

__global__ __launch_bounds__(256)
void coords_kernel(const float* __restrict__ t_enc, const float* __restrict__ Wt,
                   const float* __restrict__ bt, const float* __restrict__ q_vec,
                   float* __restrict__ coords, float* __restrict__ q_sca) {
  int item = blockIdx.x * 4 + (threadIdx.x >> 6);   // 0..4095 = b*1024 + l
  int lane = threadIdx.x & 63;
  float v = t_enc[(size_t)item * 64 + lane] * Wt[lane];
  v += __shfl_xor(v, 32);
  v += __shfl_xor(v, 16);
  v += __shfl_xor(v, 8);
  v += __shfl_xor(v, 4);
  v += __shfl_xor(v, 2);
  v += __shfl_xor(v, 1);
  if (lane == 0) {
    float z = v + bt[0];
    float tau = 1.0f / (1.0f + expf(-z));
    float c = tau * 1023.0f;
    coords[item] = c;
    float fi = floorf(c);
    int i = (int)fi;
    float t = c - fi;
    int im1 = i - 1; if (im1 < 0) im1 = 0; if (im1 > 1023) im1 = 1023;
    int i0 = i; if (i0 < 0) i0 = 0; if (i0 > 1023) i0 = 1023;
    int i1 = i + 1; if (i1 > 1023) i1 = 1023;
    int i2 = i + 2; if (i2 > 1023) i2 = 1023;
    float p0 = q_vec[im1], p1 = q_vec[i0], p2 = q_vec[i1], p3 = q_vec[i2];
    float t2 = t * t, t3 = t2 * t;
    q_sca[item] = 0.5f * (2.f * p1 + (-p0 + p2) * t +
                          (2.f * p0 - 5.f * p1 + 4.f * p2 - p3) * t2 +
                          (-p0 + 3.f * p1 - 3.f * p2 + p3) * t3);
  }
}

__global__ __launch_bounds__(256)
void convx_kernel(const float* __restrict__ x, unsigned short* __restrict__ xb,
                  unsigned short* __restrict__ xlo) {
  int i = blockIdx.x * 256 + threadIdx.x;   // 0..4194303
  float f = x[i];
  unsigned short h = f2bf(f);
  xb[i] = h;
  xlo[i] = f2bf(f - bf2f(h));
}

__global__ __launch_bounds__(256)
void convw_kernel(const float* __restrict__ w0, const float* __restrict__ w1,
                  const float* __restrict__ w2, const float* __restrict__ w3,
                  unsigned short* __restrict__ out) {
  int i = blockIdx.x * 256 + threadIdx.x;   // 0..4194303
  int sel = i >> 20;
  const float* w = (sel == 0) ? w0 : (sel == 1) ? w1 : (sel == 2) ? w2 : w3;
  out[i] = f2bf(w[i & 0xFFFFF]);
}

// ---------------- GEMM: QKV projections ----------------

__global__ __launch_bounds__(256, 2)
void gemm_qkv_kernel(const unsigned short* __restrict__ Abuf,
                     const unsigned short* __restrict__ Wb,
                     unsigned short* __restrict__ Qb,
                     unsigned short* __restrict__ Kb,
                     unsigned short* __restrict__ Vb) {
  __shared__ unsigned short As[128 * 64];
  __shared__ unsigned short Bs[128 * 64];
  const int tid = threadIdx.x, w = tid >> 6, l = tid & 63;
  const int sel = blockIdx.x >> 3;
  const int nb = (blockIdx.x & 7) * 128;
  const int m0 = blockIdx.y * 128;
  const unsigned short* Bbuf = Wb + ((size_t)sel << 20);
  const int wr = w >> 1, wc = w & 1;
  const int ll = l & 15, akg = (l >> 4) * 8;

  const f32x4 zero4 = {0.f, 0.f, 0.f, 0.f};
  f32x4 acc[4][4];
  #pragma unroll
  for (int i = 0; i < 4; ++i) {
    #pragma unroll
    for (int j = 0; j < 4; ++j) acc[i][j] = zero4;
  }

  for (int kt = 0; kt < 1024; kt += 64) {
    __syncthreads();
    #pragma unroll
    for (int q = 0; q < 4; ++q) {
      const int seg = w * 4 + q;
      const int row = seg * 8 + (l >> 3);
      const int col = kt + (l & 7) * 8;
      gload16(Abuf + (size_t)(m0 + row) * 1024 + col, &As[seg * 512 + l * 8]);
      gload16(Bbuf + (size_t)(nb + row) * 1024 + col, &Bs[seg * 512 + l * 8]);
    }
    __syncthreads();
    #pragma unroll
    for (int ks = 0; ks < 2; ++ks) {
      s8v af[4], bf[4];
      #pragma unroll
      for (int mi = 0; mi < 4; ++mi)
        af[mi] = *(const s8v*)&As[(wr * 64 + mi * 16 + ll) * 64 + ks * 32 + akg];
      #pragma unroll
      for (int ni = 0; ni < 4; ++ni)
        bf[ni] = *(const s8v*)&Bs[(wc * 64 + ni * 16 + ll) * 64 + ks * 32 + akg];
      #pragma unroll
      for (int mi = 0; mi < 4; ++mi) {
        #pragma unroll
        for (int ni = 0; ni < 4; ++ni)
          acc[mi][ni] = __builtin_amdgcn_mfma_f32_16x16x32_bf16(af[mi], bf[ni], acc[mi][ni], 0, 0, 0);
      }
    }
  }

  unsigned short* dst = (sel == 0) ? Qb : ((sel == 1) ? Kb : Vb);
  #pragma unroll
  for (int mi = 0; mi < 4; ++mi) {
    #pragma unroll
    for (int ni = 0; ni < 4; ++ni) {
      #pragma unroll
      for (int r = 0; r < 4; ++r) {
        int m = m0 + wr * 64 + mi * 16 + (l >> 4) * 4 + r;
        int ncol = nb + wc * 64 + ni * 16 + ll;
        int bb = m >> 10, lr = m & 1023, hh = ncol >> 6, dd = ncol & 63;
        dst[(((size_t)bb * 16 + hh) * 1024 + lr) * 64 + dd] = f2bf(acc[mi][ni][r]);
      }
    }
  }
}

// ---------------- GEMM: output projection ----------------

__global__ __launch_bounds__(256, 2)
void gemm_out_kernel(const unsigned short* __restrict__ Abuf,
                     const unsigned short* __restrict__ Bbuf,
                     const float* __restrict__ bO,
                     float* __restrict__ out) {
  __shared__ unsigned short As[128 * 64];
  __shared__ unsigned short Bs[128 * 64];
  const int tid = threadIdx.x, w = tid >> 6, l = tid & 63;
  const int nb = blockIdx.x * 128;
  const int m0 = blockIdx.y * 128;
  const int wr = w >> 1, wc = w & 1;
  const int ll = l & 15, akg = (l >> 4) * 8;

  const f32x4 zero4 = {0.f, 0.f, 0.f, 0.f};
  f32x4 acc[4][4];
  #pragma unroll
  for (int i = 0; i < 4; ++i) {
    #pragma unroll
    for (int j = 0; j < 4; ++j) acc[i][j] = zero4;
  }

  for (int kt = 0; kt < 1024; kt += 64) {
    __syncthreads();
    #pragma unroll
    for (int q = 0; q < 4; ++q) {
      const int seg = w * 4 + q;
      const int row = seg * 8 + (l >> 3);
      const int col = kt + (l & 7) * 8;
      gload16(Abuf + (size_t)(m0 + row) * 1024 + col, &As[seg * 512 + l * 8]);
      gload16(Bbuf + (size_t)(nb + row) * 1024 + col, &Bs[seg * 512 + l * 8]);
    }
    __syncthreads();
    #pragma unroll
    for (int ks = 0; ks < 2; ++ks) {
      s8v af[4], bf[4];
      #pragma unroll
      for (int mi = 0; mi < 4; ++mi)
        af[mi] = *(const s8v*)&As[(wr * 64 + mi * 16 + ll) * 64 + ks * 32 + akg];
      #pragma unroll
      for (int ni = 0; ni < 4; ++ni)
        bf[ni] = *(const s8v*)&Bs[(wc * 64 + ni * 16 + ll) * 64 + ks * 32 + akg];
      #pragma unroll
      for (int mi = 0; mi < 4; ++mi) {
        #pragma unroll
        for (int ni = 0; ni < 4; ++ni)
          acc[mi][ni] = __builtin_amdgcn_mfma_f32_16x16x32_bf16(af[mi], bf[ni], acc[mi][ni], 0, 0, 0);
      }
    }
  }

  #pragma unroll
  for (int mi = 0; mi < 4; ++mi) {
    #pragma unroll
    for (int ni = 0; ni < 4; ++ni) {
      #pragma unroll
      for (int r = 0; r < 4; ++r) {
        int m = m0 + wr * 64 + mi * 16 + (l >> 4) * 4 + r;
        int ncol = nb + wc * 64 + ni * 16 + ll;
        out[(size_t)m * 1024 + ncol] = acc[mi][ni][r] + bO[ncol];
      }
    }
  }
}

// ---------------- fused attention ----------------
// 512 threads (8 waves), i-tile = 128 rows (wave w owns 16). grid: 512 blocks 1-D,
// XCD-swizzled so the 8 i-blocks of one (b,h) share one XCD's L2.
// K/Ph/Pl double-buffered + pipelined via global_load_lds (swizzled source);
// V prefetched to regs one tile ahead (T14), written to LDS after the drain barrier.

__global__ __launch_bounds__(512, 4)
void attn_kernel(const unsigned short* __restrict__ Qb,
                 const unsigned short* __restrict__ Kb,
                 const unsigned short* __restrict__ Vb,
                 const unsigned short* __restrict__ xb,
                 const unsigned short* __restrict__ xlo,
                 const float* __restrict__ coords,
                 const float* __restrict__ q_sca,
                 const float* __restrict__ r_vec,
                 const float* __restrict__ alpha,
                 const float* __restrict__ beta,
                 const float* __restrict__ gamma,
                 unsigned short* __restrict__ AO) {
  __shared__ float r_s[1026];
  __shared__ unsigned short Ks[2][64 * 64];
  __shared__ unsigned short Ph[2][64 * 64];
  __shared__ unsigned short Pl[2][64 * 64];
  __shared__ unsigned short Vt[64 * 72];
  __shared__ unsigned short pbuf[8][16 * 72];

  const int tid = threadIdx.x;
  const int w = tid >> 6;
  const int l = tid & 63;
  const int gid = blockIdx.x;
  const int bh = (gid & 7) * 8 + ((gid >> 3) >> 3);   // XCD gid%8 owns 8 bh values
  const int xt = (gid >> 3) & 7;
  const int b = bh >> 4;
  const int h = bh & 15;
  const int iw = xt * 128 + w * 16;

  for (int t = tid; t < 1024; t += 512) r_s[t] = r_vec[t];
  if (tid < 2) r_s[1024 + tid] = r_vec[1023];

  const float INVLN2 = 1.4426950408889634f;
  const float a_h = alpha[h] * INVLN2, b_h = beta[h] * INVLN2, c_h = gamma[h] * INVLN2;
  const int lg = l >> 4;
  const int ll = l & 15;
  const int rowg = lg * 4;
  const int akg = lg * 8;

  float aqi[4], ci[4];
  #pragma unroll
  for (int r = 0; r < 4; ++r) {
    aqi[r] = fmaf(a_h, q_sca[b * 1024 + iw + rowg + r], c_h);
    ci[r] = coords[b * 1024 + iw + rowg + r];
  }

  s8v qf[2], pih[2], pil[2];
  {
    const unsigned short* qp = Qb + ((size_t)bh * 1024 + iw + ll) * 64 + akg;
    qf[0] = *(const s8v*)(qp);
    qf[1] = *(const s8v*)(qp + 32);
    const unsigned short* xp = xb + ((size_t)b * 1024 + iw + ll) * 1024 + h * 64 + akg;
    pih[0] = *(const s8v*)(xp);
    pih[1] = *(const s8v*)(xp + 32);
    const unsigned short* xq = xlo + ((size_t)b * 1024 + iw + ll) * 1024 + h * 64 + akg;
    pil[0] = *(const s8v*)(xq);
    pil[1] = *(const s8v*)(xq + 32);
  }

  const f32x4 zero4 = {0.f, 0.f, 0.f, 0.f};
  f32x4 o[4];
  #pragma unroll
  for (int ds = 0; ds < 4; ++ds) o[ds] = zero4;
  float mrow[4], lsum[4];
  #pragma unroll
  for (int r = 0; r < 4; ++r) { mrow[r] = -3.0e38f; lsum[r] = 0.f; }

  unsigned short* pw = pbuf[w];
  const int cs = (((l & 7) ^ ((l >> 3) & 7)) * 8);   // inverse-swizzled source col
  const int srow = l >> 3;

  auto stage = [&](int j0, int buf) {
    const int row = w * 8 + srow;
    gload16(Kb + ((size_t)bh * 1024 + j0 + row) * 64 + cs, &Ks[buf][w * 512 + l * 8]);
    gload16(xb + ((size_t)b * 1024 + j0 + row) * 1024 + h * 64 + cs, &Ph[buf][w * 512 + l * 8]);
    gload16(xlo + ((size_t)b * 1024 + j0 + row) * 1024 + h * 64 + cs, &Pl[buf][w * 512 + l * 8]);
  };
  auto vload = [&](int j0) -> s8v {
    return *(const s8v*)(Vb + ((size_t)bh * 1024 + j0 + l) * 64 + w * 8);
  };
  auto vwrite = [&](const s8v& vv) {
    #pragma unroll
    for (int e = 0; e < 8; ++e) Vt[(w * 8 + e) * 72 + l] = (unsigned short)vv[e];
  };

  // prologue: stage tiles 0,1 ; V(0),V(1) to regs; Vt <- V(0)
  stage(0, 0);
  s8v vv0 = vload(0);
  stage(64, 1);
  s8v vv1 = vload(64);
  vwrite(vv0);
  __syncthreads();

#define ATTN_TILE(T, PAR, VCONS, VPROD)                                          \
  {                                                                              \
    const int j0 = (T) * 64;                                                     \
    float cj[4], aqj[4];                                                         \
    _Pragma("unroll")                                                            \
    for (int s = 0; s < 4; ++s) {                                                \
      cj[s] = coords[b * 1024 + j0 + ll + 16 * s];                               \
      aqj[s] = a_h * q_sca[b * 1024 + j0 + ll + 16 * s];                         \
    }                                                                            \
    f32x4 aqk[4], app[4];                                                        \
    _Pragma("unroll")                                                            \
    for (int s = 0; s < 4; ++s) { aqk[s] = zero4; app[s] = zero4; }              \
    _Pragma("unroll")                                                            \
    for (int ks = 0; ks < 2; ++ks) {                                             \
      _Pragma("unroll")                                                          \
      for (int s = 0; s < 4; ++s) {                                              \
        const int rb = (ll + 16 * s) * 64 + (((ks * 4 + lg) ^ (ll & 7)) * 8);    \
        s8v kf = *(const s8v*)&Ks[PAR][rb];                                      \
        s8v hf = *(const s8v*)&Ph[PAR][rb];                                      \
        s8v lf = *(const s8v*)&Pl[PAR][rb];                                      \
        aqk[s] = __builtin_amdgcn_mfma_f32_16x16x32_bf16(qf[ks], kf, aqk[s], 0, 0, 0);   \
        app[s] = __builtin_amdgcn_mfma_f32_16x16x32_bf16(pih[ks], hf, app[s], 0, 0, 0);  \
        app[s] = __builtin_amdgcn_mfma_f32_16x16x32_bf16(pih[ks], lf, app[s], 0, 0, 0);  \
        app[s] = __builtin_amdgcn_mfma_f32_16x16x32_bf16(pil[ks], hf, app[s], 0, 0, 0);  \
      }                                                                          \
    }                                                                            \
    float tmax[4];                                                               \
    _Pragma("unroll")                                                            \
    for (int r = 0; r < 4; ++r) tmax[r] = -3.0e38f;                              \
    _Pragma("unroll")                                                            \
    for (int s = 0; s < 4; ++s) {                                                \
      _Pragma("unroll")                                                          \
      for (int r = 0; r < 4; ++r) {                                              \
        float delta = fabsf(ci[r] - cj[s]);                                      \
        int i0 = (int)delta;                                                     \
        float tt = delta - (float)i0;                                            \
        float r0 = r_s[i0];                                                      \
        float r1 = r_s[i0 + 1];                                                  \
        float rs = fmaf(tt, r1 - r0, r0);                                        \
        float S = fmaf(b_h, rs, aqi[r] + aqj[s]);                                \
        float v = fmaf(0.18033688f, aqk[s][r], S * app[s][r]);                   \
        app[s][r] = v;                                                           \
        tmax[r] = fmaxf(tmax[r], v);                                             \
      }                                                                          \
    }                                                                            \
    _Pragma("unroll")                                                            \
    for (int r = 0; r < 4; ++r) {                                                \
      float v = tmax[r];                                                         \
      v = fmaxf(v, __shfl_xor(v, 1));                                            \
      v = fmaxf(v, __shfl_xor(v, 2));                                            \
      v = fmaxf(v, __shfl_xor(v, 4));                                            \
      v = fmaxf(v, __shfl_xor(v, 8));                                            \
      float mn = fmaxf(mrow[r], v);                                              \
      float scale = exp2f(mrow[r] - mn);                                         \
      mrow[r] = mn;                                                              \
      lsum[r] *= scale;                                                          \
      o[0][r] *= scale; o[1][r] *= scale; o[2][r] *= scale; o[3][r] *= scale;    \
    }                                                                            \
    _Pragma("unroll")                                                            \
    for (int s = 0; s < 4; ++s) {                                                \
      _Pragma("unroll")                                                          \
      for (int r = 0; r < 4; ++r) {                                              \
        float e = exp2f(app[s][r] - mrow[r]);                                    \
        lsum[r] += e;                                                            \
        pw[(rowg + r) * 72 + ll + 16 * s] = f2bf(e);                             \
      }                                                                          \
    }                                                                            \
    _Pragma("unroll")                                                            \
    for (int ks = 0; ks < 2; ++ks) {                                             \
      s8v pa = *(const s8v*)&pw[ll * 72 + ks * 32 + akg];                        \
      _Pragma("unroll")                                                          \
      for (int dq = 0; dq < 4; ++dq) {                                           \
        s8v vf = *(const s8v*)&Vt[(ll + 16 * dq) * 72 + ks * 32 + akg];          \
        o[dq] = __builtin_amdgcn_mfma_f32_16x16x32_bf16(pa, vf, o[dq], 0, 0, 0); \
      }                                                                          \
    }                                                                            \
    __syncthreads();                         /* drains vmcnt: stage(T+1) is old -> free */ \
    if ((T) < 15) {                                                              \
      vwrite(VCONS);                         /* Vt <- V(T+1) */                  \
      if ((T) < 14) {                                                            \
        stage((T) + 2 > 15 ? 0 : ((T) + 2) * 64, PAR);                           \
        VPROD = vload(((T) + 2) * 64);                                           \
      }                                                                          \
      asm volatile("s_waitcnt lgkmcnt(0)" ::: "memory");                         \
      __builtin_amdgcn_sched_barrier(0);                                         \
      __builtin_amdgcn_s_barrier();                                              \
    }                                                                            \
  }

  for (int t2 = 0; t2 < 16; t2 += 2) {
    ATTN_TILE(t2, 0, vv1, vv0);
    ATTN_TILE(t2 + 1, 1, vv0, vv1);
  }
#undef ATTN_TILE

  #pragma unroll
  for (int r = 0; r < 4; ++r) {
    float v = lsum[r];
    v += __shfl_xor(v, 1);
    v += __shfl_xor(v, 2);
    v += __shfl_xor(v, 4);
    v += __shfl_xor(v, 8);
    lsum[r] = 1.0f / v;
  }
  #pragma unroll
  for (int ds = 0; ds < 4; ++ds) {
    #pragma unroll
    for (int r = 0; r < 4; ++r) {
      AO[((size_t)b * 1024 + iw + rowg + r) * 1024 + h * 64 + ll + 16 * ds] =
          f2bf(o[ds][r] * lsum[r]);
    }
  }
}

// ---------------- launcher ----------------

extern "C" void kernel_launch(void* const* d_in, const int* in_sizes, int n_in,
                              void* d_out, int out_size, void* d_ws, size_t ws_size,
                              hipStream_t stream) {
  const float* x     = (const float*)d_in[0];
  const float* t_enc = (const float*)d_in[1];
  const float* WQ    = (const float*)d_in[2];
  const float* WK    = (const float*)d_in[3];
  const float* WV    = (const float*)d_in[4];
  const float* WO    = (const float*)d_in[5];
  const float* bO    = (const float*)d_in[6];
  const float* Wt    = (const float*)d_in[7];
  const float* bt    = (const float*)d_in[8];
  const float* p_mat = (const float*)d_in[9];
  const float* r_mat = (const float*)d_in[10];
  const float* alpha = (const float*)d_in[11];
  const float* beta  = (const float*)d_in[12];
  const float* gamma = (const float*)d_in[13];
  float* out = (float*)d_out;

  char* ws = (char*)d_ws;
  unsigned short* xb  = (unsigned short*)(ws + ((size_t)0 << 20));
  unsigned short* xlo = (unsigned short*)(ws + ((size_t)8 << 20));
  unsigned short* wb  = (unsigned short*)(ws + ((size_t)16 << 20));
  unsigned short* Qb  = (unsigned short*)(ws + ((size_t)24 << 20));
  unsigned short* Kb  = (unsigned short*)(ws + ((size_t)32 << 20));
  unsigned short* Vb  = (unsigned short*)(ws + ((size_t)40 << 20));
  unsigned short* AO  = (unsigned short*)(ws + ((size_t)48 << 20));
  float* q_vec  = (float*)(ws + ((size_t)56 << 20));
  float* r_vec  = q_vec + 1024;
  float* coords = r_vec + 1024;
  float* q_sca  = coords + 4096;

  colsum_kernel<<<4, 256, 0, stream>>>(p_mat, r_mat, q_vec, r_vec);
  coords_kernel<<<1024, 256, 0, stream>>>(t_enc, Wt, bt, q_vec, coords, q_sca);
  convx_kernel<<<16384, 256, 0, stream>>>(x, xb, xlo);
  convw_kernel<<<16384, 256, 0, stream>>>(WQ, WK, WV, WO, wb);
  gemm_qkv_kernel<<<dim3(24, 32), 256, 0, stream>>>(xb, wb, Qb, Kb, Vb);
  attn_kernel<<<512, 512, 0, stream>>>(Qb, Kb, Vb, xb, xlo, coords, q_sca,
                                       r_vec, alpha, beta, gamma, AO);
  gemm_out_kernel<<<dim3(8, 32), 256, 0, stream>>>(AO, wb + ((size_t)3 << 20), bO, out);
}

// Round 4
// 332.120 us; speedup vs baseline: 1.3253x; 1.3253x over previous
//
#include <hip/hip_runtime.h>
#include <cstdint>
#include <cstddef>

typedef __attribute__((ext_vector_type(8))) short s8v;
typedef __attribute__((ext_vector_type(4))) float f32x4;

__device__ __forceinline__ unsigned short f2bf(float f) {
  unsigned int u = __builtin_bit_cast(unsigned int, f);
  unsigned int r = (u + 0x7fffu + ((u >> 16) & 1u)) >> 16;
  return (unsigned short)r;
}
__device__ __forceinline__ float bf2f(unsigned short s) {
  unsigned int u = ((unsigned int)s) << 16;
  return __builtin_bit_cast(float, u);
}

__device__ __forceinline__ void gload16(const void* g, void* l) {
  __builtin_amdgcn_global_load_lds(
      (const __attribute__((address_space(1))) void*)g,
      (__attribute__((address_space(3))) void*)l, 16, 0, 0);
}

// ---------------- prep kernels ----------------

__global__ __launch_bounds__(256)
void colsum_kernel(const float* __restrict__ p_mat, const float* __restrict__ r_mat,
                   float* __restrict__ q_vec, float* __restrict__ r_vec) {
  int l = blockIdx.x * 256 + threadIdx.x;   // 0..1023
  float sp = 0.f, sr = 0.f;
  for (int d = 0; d < 1024; ++d) {
    sp += p_mat[d * 1024 + l];
    sr += r_mat[d * 1024 + l];
  }
  q_vec[l] = sp;
  r_vec[l] = sr;
}

__global__ __launch_bounds__(256)
void coords_kernel(const float* __restrict__ t_enc, const float* __restrict__ Wt,
                   const float* __restrict__ bt, const float* __restrict__ q_vec,
                   float* __restrict__ coords, float* __restrict__ q_sca) {
  int item = blockIdx.x * 4 + (threadIdx.x >> 6);   // 0..4095 = b*1024 + l
  int lane = threadIdx.x & 63;
  float v = t_enc[(size_t)item * 64 + lane] * Wt[lane];
  v += __shfl_xor(v, 32);
  v += __shfl_xor(v, 16);
  v += __shfl_xor(v, 8);
  v += __shfl_xor(v, 4);
  v += __shfl_xor(v, 2);
  v += __shfl_xor(v, 1);
  if (lane == 0) {
    float z = v + bt[0];
    float tau = 1.0f / (1.0f + expf(-z));
    float c = tau * 1023.0f;
    coords[item] = c;
    float fi = floorf(c);
    int i = (int)fi;
    float t = c - fi;
    int im1 = i - 1; if (im1 < 0) im1 = 0; if (im1 > 1023) im1 = 1023;
    int i0 = i; if (i0 < 0) i0 = 0; if (i0 > 1023) i0 = 1023;
    int i1 = i + 1; if (i1 > 1023) i1 = 1023;
    int i2 = i + 2; if (i2 > 1023) i2 = 1023;
    float p0 = q_vec[im1], p1 = q_vec[i0], p2 = q_vec[i1], p3 = q_vec[i2];
    float t2 = t * t, t3 = t2 * t;
    q_sca[item] = 0.5f * (2.f * p1 + (-p0 + p2) * t +
                          (2.f * p0 - 5.f * p1 + 4.f * p2 - p3) * t2 +
                          (-p0 + 3.f * p1 - 3.f * p2 + p3) * t3);
  }
}

__global__ __launch_bounds__(256)
void convx_kernel(const float* __restrict__ x, unsigned short* __restrict__ xb,
                  unsigned short* __restrict__ xlo) {
  int i = blockIdx.x * 256 + threadIdx.x;   // 0..4194303
  float f = x[i];
  unsigned short h = f2bf(f);
  xb[i] = h;
  xlo[i] = f2bf(f - bf2f(h));
}

__global__ __launch_bounds__(256)
void convw_kernel(const float* __restrict__ w0, const float* __restrict__ w1,
                  const float* __restrict__ w2, const float* __restrict__ w3,
                  unsigned short* __restrict__ out) {
  int i = blockIdx.x * 256 + threadIdx.x;   // 0..4194303
  int sel = i >> 20;
  const float* w = (sel == 0) ? w0 : (sel == 1) ? w1 : (sel == 2) ? w2 : w3;
  out[i] = f2bf(w[i & 0xFFFFF]);
}

// ---------------- GEMM: QKV projections ----------------

__global__ __launch_bounds__(256, 2)
void gemm_qkv_kernel(const unsigned short* __restrict__ Abuf,
                     const unsigned short* __restrict__ Wb,
                     unsigned short* __restrict__ Qb,
                     unsigned short* __restrict__ Kb,
                     unsigned short* __restrict__ Vb) {
  __shared__ unsigned short As[128 * 64];
  __shared__ unsigned short Bs[128 * 64];
  const int tid = threadIdx.x, w = tid >> 6, l = tid & 63;
  const int sel = blockIdx.x >> 3;
  const int nb = (blockIdx.x & 7) * 128;
  const int m0 = blockIdx.y * 128;
  const unsigned short* Bbuf = Wb + ((size_t)sel << 20);
  const int wr = w >> 1, wc = w & 1;
  const int ll = l & 15, akg = (l >> 4) * 8;

  const f32x4 zero4 = {0.f, 0.f, 0.f, 0.f};
  f32x4 acc[4][4];
  #pragma unroll
  for (int i = 0; i < 4; ++i) {
    #pragma unroll
    for (int j = 0; j < 4; ++j) acc[i][j] = zero4;
  }

  for (int kt = 0; kt < 1024; kt += 64) {
    __syncthreads();
    #pragma unroll
    for (int q = 0; q < 4; ++q) {
      const int seg = w * 4 + q;
      const int row = seg * 8 + (l >> 3);
      const int col = kt + (l & 7) * 8;
      gload16(Abuf + (size_t)(m0 + row) * 1024 + col, &As[seg * 512 + l * 8]);
      gload16(Bbuf + (size_t)(nb + row) * 1024 + col, &Bs[seg * 512 + l * 8]);
    }
    __syncthreads();
    #pragma unroll
    for (int ks = 0; ks < 2; ++ks) {
      s8v af[4], bf[4];
      #pragma unroll
      for (int mi = 0; mi < 4; ++mi)
        af[mi] = *(const s8v*)&As[(wr * 64 + mi * 16 + ll) * 64 + ks * 32 + akg];
      #pragma unroll
      for (int ni = 0; ni < 4; ++ni)
        bf[ni] = *(const s8v*)&Bs[(wc * 64 + ni * 16 + ll) * 64 + ks * 32 + akg];
      #pragma unroll
      for (int mi = 0; mi < 4; ++mi) {
        #pragma unroll
        for (int ni = 0; ni < 4; ++ni)
          acc[mi][ni] = __builtin_amdgcn_mfma_f32_16x16x32_bf16(af[mi], bf[ni], acc[mi][ni], 0, 0, 0);
      }
    }
  }

  unsigned short* dst = (sel == 0) ? Qb : ((sel == 1) ? Kb : Vb);
  #pragma unroll
  for (int mi = 0; mi < 4; ++mi) {
    #pragma unroll
    for (int ni = 0; ni < 4; ++ni) {
      #pragma unroll
      for (int r = 0; r < 4; ++r) {
        int m = m0 + wr * 64 + mi * 16 + (l >> 4) * 4 + r;
        int ncol = nb + wc * 64 + ni * 16 + ll;
        int bb = m >> 10, lr = m & 1023, hh = ncol >> 6, dd = ncol & 63;
        dst[(((size_t)bb * 16 + hh) * 1024 + lr) * 64 + dd] = f2bf(acc[mi][ni][r]);
      }
    }
  }
}

// ---------------- GEMM: output projection ----------------

__global__ __launch_bounds__(256, 2)
void gemm_out_kernel(const unsigned short* __restrict__ Abuf,
                     const unsigned short* __restrict__ Bbuf,
                     const float* __restrict__ bO,
                     float* __restrict__ out) {
  __shared__ unsigned short As[128 * 64];
  __shared__ unsigned short Bs[128 * 64];
  const int tid = threadIdx.x, w = tid >> 6, l = tid & 63;
  const int nb = blockIdx.x * 128;
  const int m0 = blockIdx.y * 128;
  const int wr = w >> 1, wc = w & 1;
  const int ll = l & 15, akg = (l >> 4) * 8;

  const f32x4 zero4 = {0.f, 0.f, 0.f, 0.f};
  f32x4 acc[4][4];
  #pragma unroll
  for (int i = 0; i < 4; ++i) {
    #pragma unroll
    for (int j = 0; j < 4; ++j) acc[i][j] = zero4;
  }

  for (int kt = 0; kt < 1024; kt += 64) {
    __syncthreads();
    #pragma unroll
    for (int q = 0; q < 4; ++q) {
      const int seg = w * 4 + q;
      const int row = seg * 8 + (l >> 3);
      const int col = kt + (l & 7) * 8;
      gload16(Abuf + (size_t)(m0 + row) * 1024 + col, &As[seg * 512 + l * 8]);
      gload16(Bbuf + (size_t)(nb + row) * 1024 + col, &Bs[seg * 512 + l * 8]);
    }
    __syncthreads();
    #pragma unroll
    for (int ks = 0; ks < 2; ++ks) {
      s8v af[4], bf[4];
      #pragma unroll
      for (int mi = 0; mi < 4; ++mi)
        af[mi] = *(const s8v*)&As[(wr * 64 + mi * 16 + ll) * 64 + ks * 32 + akg];
      #pragma unroll
      for (int ni = 0; ni < 4; ++ni)
        bf[ni] = *(const s8v*)&Bs[(wc * 64 + ni * 16 + ll) * 64 + ks * 32 + akg];
      #pragma unroll
      for (int mi = 0; mi < 4; ++mi) {
        #pragma unroll
        for (int ni = 0; ni < 4; ++ni)
          acc[mi][ni] = __builtin_amdgcn_mfma_f32_16x16x32_bf16(af[mi], bf[ni], acc[mi][ni], 0, 0, 0);
      }
    }
  }

  #pragma unroll
  for (int mi = 0; mi < 4; ++mi) {
    #pragma unroll
    for (int ni = 0; ni < 4; ++ni) {
      #pragma unroll
      for (int r = 0; r < 4; ++r) {
        int m = m0 + wr * 64 + mi * 16 + (l >> 4) * 4 + r;
        int ncol = nb + wc * 64 + ni * 16 + ll;
        out[(size_t)m * 1024 + ncol] = acc[mi][ni][r] + bO[ncol];
      }
    }
  }
}

// ---------------- fused attention ----------------
// 512 threads (8 waves), i-tile = 128 rows (wave w owns 16). grid: 512 blocks 1-D,
// XCD-swizzled so the 8 i-blocks of one (b,h) share one XCD's L2.
// __launch_bounds__(512, 2): 2 blocks/CU -> 4 waves/SIMD -> 128-VGPR budget (no spills;
// round 3's (512,4) forced 64 VGPRs and 860 MB of scratch traffic).

__global__ __launch_bounds__(512, 2)
void attn_kernel(const unsigned short* __restrict__ Qb,
                 const unsigned short* __restrict__ Kb,
                 const unsigned short* __restrict__ Vb,
                 const unsigned short* __restrict__ xb,
                 const unsigned short* __restrict__ xlo,
                 const float* __restrict__ coords,
                 const float* __restrict__ q_sca,
                 const float* __restrict__ r_vec,
                 const float* __restrict__ alpha,
                 const float* __restrict__ beta,
                 const float* __restrict__ gamma,
                 unsigned short* __restrict__ AO) {
  __shared__ float r_s[1026];
  __shared__ unsigned short Ks[2][64 * 64];
  __shared__ unsigned short Ph[2][64 * 64];
  __shared__ unsigned short Pl[2][64 * 64];
  __shared__ unsigned short Vt[64 * 72];
  __shared__ unsigned short pbuf[8][16 * 72];

  const int tid = threadIdx.x;
  const int w = tid >> 6;
  const int l = tid & 63;
  const int gid = blockIdx.x;
  const int bh = (gid & 7) * 8 + ((gid >> 3) >> 3);   // XCD gid%8 owns 8 bh values
  const int xt = (gid >> 3) & 7;
  const int b = bh >> 4;
  const int h = bh & 15;
  const int iw = xt * 128 + w * 16;

  for (int t = tid; t < 1024; t += 512) r_s[t] = r_vec[t];
  if (tid < 2) r_s[1024 + tid] = r_vec[1023];

  const float INVLN2 = 1.4426950408889634f;
  const float a_h = alpha[h] * INVLN2, b_h = beta[h] * INVLN2, c_h = gamma[h] * INVLN2;
  const int lg = l >> 4;
  const int ll = l & 15;
  const int rowg = lg * 4;
  const int akg = lg * 8;

  float aqi[4], ci[4];
  #pragma unroll
  for (int r = 0; r < 4; ++r) {
    aqi[r] = fmaf(a_h, q_sca[b * 1024 + iw + rowg + r], c_h);
    ci[r] = coords[b * 1024 + iw + rowg + r];
  }

  s8v qf[2], pih[2], pil[2];
  {
    const unsigned short* qp = Qb + ((size_t)bh * 1024 + iw + ll) * 64 + akg;
    qf[0] = *(const s8v*)(qp);
    qf[1] = *(const s8v*)(qp + 32);
    const unsigned short* xp = xb + ((size_t)b * 1024 + iw + ll) * 1024 + h * 64 + akg;
    pih[0] = *(const s8v*)(xp);
    pih[1] = *(const s8v*)(xp + 32);
    const unsigned short* xq = xlo + ((size_t)b * 1024 + iw + ll) * 1024 + h * 64 + akg;
    pil[0] = *(const s8v*)(xq);
    pil[1] = *(const s8v*)(xq + 32);
  }

  const f32x4 zero4 = {0.f, 0.f, 0.f, 0.f};
  f32x4 o[4];
  #pragma unroll
  for (int ds = 0; ds < 4; ++ds) o[ds] = zero4;
  float mrow[4], lsum[4];
  #pragma unroll
  for (int r = 0; r < 4; ++r) { mrow[r] = -3.0e38f; lsum[r] = 0.f; }

  unsigned short* pw = pbuf[w];
  const int cs = (((l & 7) ^ ((l >> 3) & 7)) * 8);   // inverse-swizzled source col
  const int srow = l >> 3;

  auto stage = [&](int j0, int buf) {
    const int row = w * 8 + srow;
    gload16(Kb + ((size_t)bh * 1024 + j0 + row) * 64 + cs, &Ks[buf][w * 512 + l * 8]);
    gload16(xb + ((size_t)b * 1024 + j0 + row) * 1024 + h * 64 + cs, &Ph[buf][w * 512 + l * 8]);
    gload16(xlo + ((size_t)b * 1024 + j0 + row) * 1024 + h * 64 + cs, &Pl[buf][w * 512 + l * 8]);
  };
  auto vload = [&](int j0) -> s8v {
    return *(const s8v*)(Vb + ((size_t)bh * 1024 + j0 + l) * 64 + w * 8);
  };
  auto vwrite = [&](const s8v& vv) {
    #pragma unroll
    for (int e = 0; e < 8; ++e) Vt[(w * 8 + e) * 72 + l] = (unsigned short)vv[e];
  };

  // prologue: stage tiles 0,1 ; V(0),V(1) to regs; Vt <- V(0)
  stage(0, 0);
  s8v vv0 = vload(0);
  stage(64, 1);
  s8v vv1 = vload(64);
  vwrite(vv0);
  __syncthreads();

#define ATTN_TILE(T, PAR, VCONS, VPROD)                                          \
  {                                                                              \
    const int j0 = (T) * 64;                                                     \
    float cj[4], aqj[4];                                                         \
    _Pragma("unroll")                                                            \
    for (int s = 0; s < 4; ++s) {                                                \
      cj[s] = coords[b * 1024 + j0 + ll + 16 * s];                               \
      aqj[s] = a_h * q_sca[b * 1024 + j0 + ll + 16 * s];                         \
    }                                                                            \
    f32x4 aqk[4], app[4];                                                        \
    _Pragma("unroll")                                                            \
    for (int s = 0; s < 4; ++s) { aqk[s] = zero4; app[s] = zero4; }              \
    _Pragma("unroll")                                                            \
    for (int ks = 0; ks < 2; ++ks) {                                             \
      _Pragma("unroll")                                                          \
      for (int s = 0; s < 4; ++s) {                                              \
        const int rb = (ll + 16 * s) * 64 + (((ks * 4 + lg) ^ (ll & 7)) * 8);    \
        s8v kf = *(const s8v*)&Ks[PAR][rb];                                      \
        s8v hf = *(const s8v*)&Ph[PAR][rb];                                      \
        s8v lf = *(const s8v*)&Pl[PAR][rb];                                      \
        aqk[s] = __builtin_amdgcn_mfma_f32_16x16x32_bf16(qf[ks], kf, aqk[s], 0, 0, 0);   \
        app[s] = __builtin_amdgcn_mfma_f32_16x16x32_bf16(pih[ks], hf, app[s], 0, 0, 0);  \
        app[s] = __builtin_amdgcn_mfma_f32_16x16x32_bf16(pih[ks], lf, app[s], 0, 0, 0);  \
        app[s] = __builtin_amdgcn_mfma_f32_16x16x32_bf16(pil[ks], hf, app[s], 0, 0, 0);  \
      }                                                                          \
    }                                                                            \
    float tmax[4];                                                               \
    _Pragma("unroll")                                                            \
    for (int r = 0; r < 4; ++r) tmax[r] = -3.0e38f;                              \
    _Pragma("unroll")                                                            \
    for (int s = 0; s < 4; ++s) {                                                \
      _Pragma("unroll")                                                          \
      for (int r = 0; r < 4; ++r) {                                              \
        float delta = fabsf(ci[r] - cj[s]);                                      \
        int i0 = (int)delta;                                                     \
        float tt = delta - (float)i0;                                            \
        float r0 = r_s[i0];                                                      \
        float r1 = r_s[i0 + 1];                                                  \
        float rs = fmaf(tt, r1 - r0, r0);                                        \
        float S = fmaf(b_h, rs, aqi[r] + aqj[s]);                                \
        float v = fmaf(0.18033688f, aqk[s][r], S * app[s][r]);                   \
        app[s][r] = v;                                                           \
        tmax[r] = fmaxf(tmax[r], v);                                             \
      }                                                                          \
    }                                                                            \
    _Pragma("unroll")                                                            \
    for (int r = 0; r < 4; ++r) {                                                \
      float v = tmax[r];                                                         \
      v = fmaxf(v, __shfl_xor(v, 1));                                            \
      v = fmaxf(v, __shfl_xor(v, 2));                                            \
      v = fmaxf(v, __shfl_xor(v, 4));                                            \
      v = fmaxf(v, __shfl_xor(v, 8));                                            \
      float mn = fmaxf(mrow[r], v);                                              \
      float scale = exp2f(mrow[r] - mn);                                         \
      mrow[r] = mn;                                                              \
      lsum[r] *= scale;                                                          \
      o[0][r] *= scale; o[1][r] *= scale; o[2][r] *= scale; o[3][r] *= scale;    \
    }                                                                            \
    _Pragma("unroll")                                                            \
    for (int s = 0; s < 4; ++s) {                                                \
      _Pragma("unroll")                                                          \
      for (int r = 0; r < 4; ++r) {                                              \
        float e = exp2f(app[s][r] - mrow[r]);                                    \
        lsum[r] += e;                                                            \
        pw[(rowg + r) * 72 + ll + 16 * s] = f2bf(e);                             \
      }                                                                          \
    }                                                                            \
    _Pragma("unroll")                                                            \
    for (int ks = 0; ks < 2; ++ks) {                                             \
      s8v pa = *(const s8v*)&pw[ll * 72 + ks * 32 + akg];                        \
      _Pragma("unroll")                                                          \
      for (int dq = 0; dq < 4; ++dq) {                                           \
        s8v vf = *(const s8v*)&Vt[(ll + 16 * dq) * 72 + ks * 32 + akg];          \
        o[dq] = __builtin_amdgcn_mfma_f32_16x16x32_bf16(pa, vf, o[dq], 0, 0, 0); \
      }                                                                          \
    }                                                                            \
    __syncthreads();                         /* drains vmcnt: stage(T+1) is old -> free */ \
    if ((T) < 15) {                                                              \
      vwrite(VCONS);                         /* Vt <- V(T+1) */                  \
      if ((T) < 14) {                                                            \
        stage((T) + 2 > 15 ? 0 : ((T) + 2) * 64, PAR);                           \
        VPROD = vload(((T) + 2) * 64);                                           \
      }                                                                          \
      asm volatile("s_waitcnt lgkmcnt(0)" ::: "memory");                         \
      __builtin_amdgcn_sched_barrier(0);                                         \
      __builtin_amdgcn_s_barrier();                                              \
    }                                                                            \
  }

  for (int t2 = 0; t2 < 16; t2 += 2) {
    ATTN_TILE(t2, 0, vv1, vv0);
    ATTN_TILE(t2 + 1, 1, vv0, vv1);
  }
#undef ATTN_TILE

  #pragma unroll
  for (int r = 0; r < 4; ++r) {
    float v = lsum[r];
    v += __shfl_xor(v, 1);
    v += __shfl_xor(v, 2);
    v += __shfl_xor(v, 4);
    v += __shfl_xor(v, 8);
    lsum[r] = 1.0f / v;
  }
  #pragma unroll
  for (int ds = 0; ds < 4; ++ds) {
    #pragma unroll
    for (int r = 0; r < 4; ++r) {
      AO[((size_t)b * 1024 + iw + rowg + r) * 1024 + h * 64 + ll + 16 * ds] =
          f2bf(o[ds][r] * lsum[r]);
    }
  }
}

// ---------------- launcher ----------------

extern "C" void kernel_launch(void* const* d_in, const int* in_sizes, int n_in,
                              void* d_out, int out_size, void* d_ws, size_t ws_size,
                              hipStream_t stream) {
  const float* x     = (const float*)d_in[0];
  const float* t_enc = (const float*)d_in[1];
  const float* WQ    = (const float*)d_in[2];
  const float* WK    = (const float*)d_in[3];
  const float* WV    = (const float*)d_in[4];
  const float* WO    = (const float*)d_in[5];
  const float* bO    = (const float*)d_in[6];
  const float* Wt    = (const float*)d_in[7];
  const float* bt    = (const float*)d_in[8];
  const float* p_mat = (const float*)d_in[9];
  const float* r_mat = (const float*)d_in[10];
  const float* alpha = (const float*)d_in[11];
  const float* beta  = (const float*)d_in[12];
  const float* gamma = (const float*)d_in[13];
  float* out = (float*)d_out;

  char* ws = (char*)d_ws;
  unsigned short* xb  = (unsigned short*)(ws + ((size_t)0 << 20));
  unsigned short* xlo = (unsigned short*)(ws + ((size_t)8 << 20));
  unsigned short* wb  = (unsigned short*)(ws + ((size_t)16 << 20));
  unsigned short* Qb  = (unsigned short*)(ws + ((size_t)24 << 20));
  unsigned short* Kb  = (unsigned short*)(ws + ((size_t)32 << 20));
  unsigned short* Vb  = (unsigned short*)(ws + ((size_t)40 << 20));
  unsigned short* AO  = (unsigned short*)(ws + ((size_t)48 << 20));
  float* q_vec  = (float*)(ws + ((size_t)56 << 20));
  float* r_vec  = q_vec + 1024;
  float* coords = r_vec + 1024;
  float* q_sca  = coords + 4096;

  colsum_kernel<<<4, 256, 0, stream>>>(p_mat, r_mat, q_vec, r_vec);
  coords_kernel<<<1024, 256, 0, stream>>>(t_enc, Wt, bt, q_vec, coords, q_sca);
  convx_kernel<<<16384, 256, 0, stream>>>(x, xb, xlo);
  convw_kernel<<<16384, 256, 0, stream>>>(WQ, WK, WV, WO, wb);
  gemm_qkv_kernel<<<dim3(24, 32), 256, 0, stream>>>(xb, wb, Qb, Kb, Vb);
  attn_kernel<<<512, 512, 0, stream>>>(Qb, Kb, Vb, xb, xlo, coords, q_sca,
                                       r_vec, alpha, beta, gamma, AO);
  gemm_out_kernel<<<dim3(8, 32), 256, 0, stream>>>(AO, wb + ((size_t)3 << 20), bO, out);
}

// Round 5
// 289.790 us; speedup vs baseline: 1.5189x; 1.1461x over previous
//
#include <hip/hip_runtime.h>
#include <cstdint>
#include <cstddef>

typedef __attribute__((ext_vector_type(8))) short s8v;
typedef __attribute__((ext_vector_type(4))) float f32x4;

__device__ __forceinline__ unsigned short f2bf(float f) {
  unsigned int u = __builtin_bit_cast(unsigned int, f);
  unsigned int r = (u + 0x7fffu + ((u >> 16) & 1u)) >> 16;
  return (unsigned short)r;
}
__device__ __forceinline__ float bf2f(unsigned short s) {
  unsigned int u = ((unsigned int)s) << 16;
  return __builtin_bit_cast(float, u);
}

__device__ __forceinline__ void gload16(const void* g, void* l) {
  __builtin_amdgcn_global_load_lds(
      (const __attribute__((address_space(1))) void*)g,
      (__attribute__((address_space(3))) void*)l, 16, 0, 0);
}

// ---------------- prep kernels ----------------

// parallel column-sum: grid (4, 32), atomicAdd into zeroed q_vec/r_vec
__global__ __launch_bounds__(256)
void colsum_kernel(const float* __restrict__ p_mat, const float* __restrict__ r_mat,
                   float* __restrict__ q_vec, float* __restrict__ r_vec) {
  int col = blockIdx.x * 256 + threadIdx.x;   // 0..1023
  int d0 = blockIdx.y * 32;
  float sp = 0.f, sr = 0.f;
  for (int d = d0; d < d0 + 32; ++d) {
    sp += p_mat[d * 1024 + col];
    sr += r_mat[d * 1024 + col];
  }
  atomicAdd(&q_vec[col], sp);
  atomicAdd(&r_vec[col], sr);
}

__global__ __launch_bounds__(256)
void coords_kernel(const float* __restrict__ t_enc, const float* __restrict__ Wt,
                   const float* __restrict__ bt, const float* __restrict__ q_vec,
                   float* __restrict__ coords, float* __restrict__ q_sca) {
  int item = blockIdx.x * 4 + (threadIdx.x >> 6);   // 0..4095 = b*1024 + l
  int lane = threadIdx.x & 63;
  float v = t_enc[(size_t)item * 64 + lane] * Wt[lane];
  v += __shfl_xor(v, 32);
  v += __shfl_xor(v, 16);
  v += __shfl_xor(v, 8);
  v += __shfl_xor(v, 4);
  v += __shfl_xor(v, 2);
  v += __shfl_xor(v, 1);
  if (lane == 0) {
    float z = v + bt[0];
    float tau = 1.0f / (1.0f + expf(-z));
    float c = tau * 1023.0f;
    coords[item] = c;
    float fi = floorf(c);
    int i = (int)fi;
    float t = c - fi;
    int im1 = i - 1; if (im1 < 0) im1 = 0; if (im1 > 1023) im1 = 1023;
    int i0 = i; if (i0 < 0) i0 = 0; if (i0 > 1023) i0 = 1023;
    int i1 = i + 1; if (i1 > 1023) i1 = 1023;
    int i2 = i + 2; if (i2 > 1023) i2 = 1023;
    float p0 = q_vec[im1], p1 = q_vec[i0], p2 = q_vec[i1], p3 = q_vec[i2];
    float t2 = t * t, t3 = t2 * t;
    q_sca[item] = 0.5f * (2.f * p1 + (-p0 + p2) * t +
                          (2.f * p0 - 5.f * p1 + 4.f * p2 - p3) * t2 +
                          (-p0 + 3.f * p1 - 3.f * p2 + p3) * t3);
  }
}

// merged convx + convw: blocks [0,16384) convert x -> hi/lo bf16; rest convert weights
__global__ __launch_bounds__(256)
void conv_all_kernel(const float* __restrict__ x,
                     const float* __restrict__ w0, const float* __restrict__ w1,
                     const float* __restrict__ w2, const float* __restrict__ w3,
                     unsigned short* __restrict__ xb, unsigned short* __restrict__ xlo,
                     unsigned short* __restrict__ wb) {
  int bx = blockIdx.x;
  if (bx < 16384) {
    int i = bx * 256 + threadIdx.x;
    float f = x[i];
    unsigned short h = f2bf(f);
    xb[i] = h;
    xlo[i] = f2bf(f - bf2f(h));
  } else {
    int i = (bx - 16384) * 256 + threadIdx.x;
    int sel = i >> 20;
    const float* w = (sel == 0) ? w0 : (sel == 1) ? w1 : (sel == 2) ? w2 : w3;
    wb[i] = f2bf(w[i & 0xFFFFF]);
  }
}

// ---------------- GEMM: QKV projections ----------------
// C = A(4096x1024) * B^T. grid (24, 32). 128x128 tile, BK=64, 4 waves.
// Double-buffered LDS pipeline (stage k+1 during compute k) + coalesced
// LDS-transpose epilogue (b128 stores).

__global__ __launch_bounds__(256, 2)
void gemm_qkv_kernel(const unsigned short* __restrict__ Abuf,
                     const unsigned short* __restrict__ Wb,
                     unsigned short* __restrict__ Qb,
                     unsigned short* __restrict__ Kb,
                     unsigned short* __restrict__ Vb) {
  __shared__ unsigned short As[2][128 * 64];
  __shared__ unsigned short Bs[2][128 * 64];
  const int tid = threadIdx.x, w = tid >> 6, l = tid & 63;
  const int sel = blockIdx.x >> 3;
  const int nb = (blockIdx.x & 7) * 128;
  const int m0 = blockIdx.y * 128;
  const unsigned short* Bbuf = Wb + ((size_t)sel << 20);
  const int wr = w >> 1, wc = w & 1;
  const int ll = l & 15, lg = l >> 4, akg = lg * 8;

  const f32x4 zero4 = {0.f, 0.f, 0.f, 0.f};
  f32x4 acc[4][4];
  #pragma unroll
  for (int i = 0; i < 4; ++i) {
    #pragma unroll
    for (int j = 0; j < 4; ++j) acc[i][j] = zero4;
  }

  auto stage = [&](int kt, int buf) {
    #pragma unroll
    for (int q = 0; q < 4; ++q) {
      const int seg = w * 4 + q;
      const int row = seg * 8 + (l >> 3);
      const int col = kt * 64 + (l & 7) * 8;
      gload16(Abuf + (size_t)(m0 + row) * 1024 + col, &As[buf][seg * 512 + l * 8]);
      gload16(Bbuf + (size_t)(nb + row) * 1024 + col, &Bs[buf][seg * 512 + l * 8]);
    }
  };

  stage(0, 0);
  for (int kt = 0; kt < 16; ++kt) {
    __syncthreads();                    // drains vmcnt: tile kt ready (staged last iter)
    if (kt < 15) stage(kt + 1, (kt + 1) & 1);
    const int bb = kt & 1;
    #pragma unroll
    for (int ks = 0; ks < 2; ++ks) {
      s8v af[4], bf[4];
      #pragma unroll
      for (int mi = 0; mi < 4; ++mi)
        af[mi] = *(const s8v*)&As[bb][(wr * 64 + mi * 16 + ll) * 64 + ks * 32 + akg];
      #pragma unroll
      for (int ni = 0; ni < 4; ++ni)
        bf[ni] = *(const s8v*)&Bs[bb][(wc * 64 + ni * 16 + ll) * 64 + ks * 32 + akg];
      __builtin_amdgcn_s_setprio(1);
      #pragma unroll
      for (int mi = 0; mi < 4; ++mi) {
        #pragma unroll
        for (int ni = 0; ni < 4; ++ni)
          acc[mi][ni] = __builtin_amdgcn_mfma_f32_16x16x32_bf16(af[mi], bf[ni], acc[mi][ni], 0, 0, 0);
      }
      __builtin_amdgcn_s_setprio(0);
    }
  }

  // coalesced epilogue via LDS transpose: 4 chunks of 32 rows x 128 cols (pad 136)
  unsigned short* dst = (sel == 0) ? Qb : ((sel == 1) ? Kb : Vb);
  unsigned short* ch = &As[0][0];       // 32*136 = 4352 shorts
  const int err = tid >> 3;             // epilogue read row 0..31
  const int ecb = tid & 7;              // epilogue col block 0..7
  #pragma unroll
  for (int mi = 0; mi < 4; ++mi) {
    __syncthreads();
    #pragma unroll
    for (int ni = 0; ni < 4; ++ni) {
      #pragma unroll
      for (int r = 0; r < 4; ++r)
        ch[(wr * 16 + lg * 4 + r) * 136 + wc * 64 + ni * 16 + ll] = f2bf(acc[mi][ni][r]);
    }
    __syncthreads();
    int m = m0 + (err >> 4) * 64 + mi * 16 + (err & 15);
    int ncol = nb + ecb * 16;
    int bb2 = m >> 10, lr = m & 1023, hh = ncol >> 6, dd = ncol & 63;
    unsigned short* gp = &dst[(((size_t)bb2 * 16 + hh) * 1024 + lr) * 64 + dd];
    *(s8v*)(gp)     = *(const s8v*)&ch[err * 136 + ecb * 16];
    *(s8v*)(gp + 8) = *(const s8v*)&ch[err * 136 + ecb * 16 + 8];
  }
}

// ---------------- GEMM: output projection ----------------
// out(4096x1024) = AO(4096x1024 bf16) * WO^T + bO ; grid (8, 32); dbuf pipeline.

__global__ __launch_bounds__(256, 2)
void gemm_out_kernel(const unsigned short* __restrict__ Abuf,
                     const unsigned short* __restrict__ Bbuf,
                     const float* __restrict__ bO,
                     float* __restrict__ out) {
  __shared__ unsigned short As[2][128 * 64];
  __shared__ unsigned short Bs[2][128 * 64];
  const int tid = threadIdx.x, w = tid >> 6, l = tid & 63;
  const int nb = blockIdx.x * 128;
  const int m0 = blockIdx.y * 128;
  const int wr = w >> 1, wc = w & 1;
  const int ll = l & 15, akg = (l >> 4) * 8;

  const f32x4 zero4 = {0.f, 0.f, 0.f, 0.f};
  f32x4 acc[4][4];
  #pragma unroll
  for (int i = 0; i < 4; ++i) {
    #pragma unroll
    for (int j = 0; j < 4; ++j) acc[i][j] = zero4;
  }

  auto stage = [&](int kt, int buf) {
    #pragma unroll
    for (int q = 0; q < 4; ++q) {
      const int seg = w * 4 + q;
      const int row = seg * 8 + (l >> 3);
      const int col = kt * 64 + (l & 7) * 8;
      gload16(Abuf + (size_t)(m0 + row) * 1024 + col, &As[buf][seg * 512 + l * 8]);
      gload16(Bbuf + (size_t)(nb + row) * 1024 + col, &Bs[buf][seg * 512 + l * 8]);
    }
  };

  stage(0, 0);
  for (int kt = 0; kt < 16; ++kt) {
    __syncthreads();
    if (kt < 15) stage(kt + 1, (kt + 1) & 1);
    const int bb = kt & 1;
    #pragma unroll
    for (int ks = 0; ks < 2; ++ks) {
      s8v af[4], bf[4];
      #pragma unroll
      for (int mi = 0; mi < 4; ++mi)
        af[mi] = *(const s8v*)&As[bb][(wr * 64 + mi * 16 + ll) * 64 + ks * 32 + akg];
      #pragma unroll
      for (int ni = 0; ni < 4; ++ni)
        bf[ni] = *(const s8v*)&Bs[bb][(wc * 64 + ni * 16 + ll) * 64 + ks * 32 + akg];
      __builtin_amdgcn_s_setprio(1);
      #pragma unroll
      for (int mi = 0; mi < 4; ++mi) {
        #pragma unroll
        for (int ni = 0; ni < 4; ++ni)
          acc[mi][ni] = __builtin_amdgcn_mfma_f32_16x16x32_bf16(af[mi], bf[ni], acc[mi][ni], 0, 0, 0);
      }
      __builtin_amdgcn_s_setprio(0);
    }
  }

  #pragma unroll
  for (int mi = 0; mi < 4; ++mi) {
    #pragma unroll
    for (int ni = 0; ni < 4; ++ni) {
      #pragma unroll
      for (int r = 0; r < 4; ++r) {
        int m = m0 + wr * 64 + mi * 16 + (l >> 4) * 4 + r;
        int ncol = nb + wc * 64 + ni * 16 + ll;
        out[(size_t)m * 1024 + ncol] = acc[mi][ni][r] + bO[ncol];
      }
    }
  }
}

// ---------------- fused attention ----------------
// 512 threads (8 waves), i-tile = 128 rows (wave w owns 16). grid: 512 blocks 1-D,
// XCD-swizzled. __launch_bounds__(512,2) => 128-VGPR budget, no spills.

__global__ __launch_bounds__(512, 2)
void attn_kernel(const unsigned short* __restrict__ Qb,
                 const unsigned short* __restrict__ Kb,
                 const unsigned short* __restrict__ Vb,
                 const unsigned short* __restrict__ xb,
                 const unsigned short* __restrict__ xlo,
                 const float* __restrict__ coords,
                 const float* __restrict__ q_sca,
                 const float* __restrict__ r_vec,
                 const float* __restrict__ alpha,
                 const float* __restrict__ beta,
                 const float* __restrict__ gamma,
                 unsigned short* __restrict__ AO) {
  __shared__ float r_s[1026];
  __shared__ unsigned short Ks[2][64 * 64];
  __shared__ unsigned short Ph[2][64 * 64];
  __shared__ unsigned short Pl[2][64 * 64];
  __shared__ unsigned short Vt[64 * 72];
  __shared__ unsigned short pbuf[8][16 * 72];

  const int tid = threadIdx.x;
  const int w = tid >> 6;
  const int l = tid & 63;
  const int gid = blockIdx.x;
  const int bh = (gid & 7) * 8 + ((gid >> 3) >> 3);   // XCD gid%8 owns 8 bh values
  const int xt = (gid >> 3) & 7;
  const int b = bh >> 4;
  const int h = bh & 15;
  const int iw = xt * 128 + w * 16;

  for (int t = tid; t < 1024; t += 512) r_s[t] = r_vec[t];
  if (tid < 2) r_s[1024 + tid] = r_vec[1023];

  const float INVLN2 = 1.4426950408889634f;
  const float a_h = alpha[h] * INVLN2, b_h = beta[h] * INVLN2, c_h = gamma[h] * INVLN2;
  const int lg = l >> 4;
  const int ll = l & 15;
  const int rowg = lg * 4;
  const int akg = lg * 8;

  float aqi[4], ci[4];
  #pragma unroll
  for (int r = 0; r < 4; ++r) {
    aqi[r] = fmaf(a_h, q_sca[b * 1024 + iw + rowg + r], c_h);
    ci[r] = coords[b * 1024 + iw + rowg + r];
  }

  s8v qf[2], pih[2], pil[2];
  {
    const unsigned short* qp = Qb + ((size_t)bh * 1024 + iw + ll) * 64 + akg;
    qf[0] = *(const s8v*)(qp);
    qf[1] = *(const s8v*)(qp + 32);
    const unsigned short* xp = xb + ((size_t)b * 1024 + iw + ll) * 1024 + h * 64 + akg;
    pih[0] = *(const s8v*)(xp);
    pih[1] = *(const s8v*)(xp + 32);
    const unsigned short* xq = xlo + ((size_t)b * 1024 + iw + ll) * 1024 + h * 64 + akg;
    pil[0] = *(const s8v*)(xq);
    pil[1] = *(const s8v*)(xq + 32);
  }

  const f32x4 zero4 = {0.f, 0.f, 0.f, 0.f};
  f32x4 o[4];
  #pragma unroll
  for (int ds = 0; ds < 4; ++ds) o[ds] = zero4;
  float mrow[4], lsum[4];
  #pragma unroll
  for (int r = 0; r < 4; ++r) { mrow[r] = -3.0e38f; lsum[r] = 0.f; }

  unsigned short* pw = pbuf[w];
  const int cs = (((l & 7) ^ ((l >> 3) & 7)) * 8);   // inverse-swizzled source col
  const int srow = l >> 3;

  auto stage = [&](int j0, int buf) {
    const int row = w * 8 + srow;
    gload16(Kb + ((size_t)bh * 1024 + j0 + row) * 64 + cs, &Ks[buf][w * 512 + l * 8]);
    gload16(xb + ((size_t)b * 1024 + j0 + row) * 1024 + h * 64 + cs, &Ph[buf][w * 512 + l * 8]);
    gload16(xlo + ((size_t)b * 1024 + j0 + row) * 1024 + h * 64 + cs, &Pl[buf][w * 512 + l * 8]);
  };
  auto vload = [&](int j0) -> s8v {
    return *(const s8v*)(Vb + ((size_t)bh * 1024 + j0 + l) * 64 + w * 8);
  };
  auto vwrite = [&](const s8v& vv) {
    #pragma unroll
    for (int e = 0; e < 8; ++e) Vt[(w * 8 + e) * 72 + l] = (unsigned short)vv[e];
  };

  // prologue: stage tiles 0,1 ; V(0),V(1) to regs; Vt <- V(0)
  stage(0, 0);
  s8v vv0 = vload(0);
  stage(64, 1);
  s8v vv1 = vload(64);
  vwrite(vv0);
  __syncthreads();

#define ATTN_TILE(T, PAR, VCONS, VPROD)                                          \
  {                                                                              \
    const int j0 = (T) * 64;                                                     \
    float cj[4], aqj[4];                                                         \
    _Pragma("unroll")                                                            \
    for (int s = 0; s < 4; ++s) {                                                \
      cj[s] = coords[b * 1024 + j0 + ll + 16 * s];                               \
      aqj[s] = a_h * q_sca[b * 1024 + j0 + ll + 16 * s];                         \
    }                                                                            \
    f32x4 aqk[4], app[4];                                                        \
    _Pragma("unroll")                                                            \
    for (int s = 0; s < 4; ++s) { aqk[s] = zero4; app[s] = zero4; }              \
    _Pragma("unroll")                                                            \
    for (int ks = 0; ks < 2; ++ks) {                                             \
      _Pragma("unroll")                                                          \
      for (int s = 0; s < 4; ++s) {                                              \
        const int rb = (ll + 16 * s) * 64 + (((ks * 4 + lg) ^ (ll & 7)) * 8);    \
        s8v kf = *(const s8v*)&Ks[PAR][rb];                                      \
        s8v hf = *(const s8v*)&Ph[PAR][rb];                                      \
        s8v lf = *(const s8v*)&Pl[PAR][rb];                                      \
        __builtin_amdgcn_s_setprio(1);                                           \
        aqk[s] = __builtin_amdgcn_mfma_f32_16x16x32_bf16(qf[ks], kf, aqk[s], 0, 0, 0);   \
        app[s] = __builtin_amdgcn_mfma_f32_16x16x32_bf16(pih[ks], hf, app[s], 0, 0, 0);  \
        app[s] = __builtin_amdgcn_mfma_f32_16x16x32_bf16(pih[ks], lf, app[s], 0, 0, 0);  \
        app[s] = __builtin_amdgcn_mfma_f32_16x16x32_bf16(pil[ks], hf, app[s], 0, 0, 0);  \
        __builtin_amdgcn_s_setprio(0);                                           \
      }                                                                          \
    }                                                                            \
    float tmax[4];                                                               \
    _Pragma("unroll")                                                            \
    for (int r = 0; r < 4; ++r) tmax[r] = -3.0e38f;                              \
    _Pragma("unroll")                                                            \
    for (int s = 0; s < 4; ++s) {                                                \
      _Pragma("unroll")                                                          \
      for (int r = 0; r < 4; ++r) {                                              \
        float delta = fabsf(ci[r] - cj[s]);                                      \
        int i0 = (int)delta;                                                     \
        float tt = delta - (float)i0;                                            \
        float r0 = r_s[i0];                                                      \
        float r1 = r_s[i0 + 1];                                                  \
        float rs = fmaf(tt, r1 - r0, r0);                                        \
        float S = fmaf(b_h, rs, aqi[r] + aqj[s]);                                \
        float v = fmaf(0.18033688f, aqk[s][r], S * app[s][r]);                   \
        app[s][r] = v;                                                           \
        tmax[r] = fmaxf(tmax[r], v);                                             \
      }                                                                          \
    }                                                                            \
    _Pragma("unroll")                                                            \
    for (int r = 0; r < 4; ++r) {                                                \
      float v = tmax[r];                                                         \
      v = fmaxf(v, __shfl_xor(v, 1));                                            \
      v = fmaxf(v, __shfl_xor(v, 2));                                            \
      v = fmaxf(v, __shfl_xor(v, 4));                                            \
      v = fmaxf(v, __shfl_xor(v, 8));                                            \
      float mn = fmaxf(mrow[r], v);                                              \
      float scale = exp2f(mrow[r] - mn);                                         \
      mrow[r] = mn;                                                              \
      lsum[r] *= scale;                                                          \
      o[0][r] *= scale; o[1][r] *= scale; o[2][r] *= scale; o[3][r] *= scale;    \
    }                                                                            \
    _Pragma("unroll")                                                            \
    for (int s = 0; s < 4; ++s) {                                                \
      _Pragma("unroll")                                                          \
      for (int r = 0; r < 4; ++r) {                                              \
        float e = exp2f(app[s][r] - mrow[r]);                                    \
        lsum[r] += e;                                                            \
        pw[(rowg + r) * 72 + ll + 16 * s] = f2bf(e);                             \
      }                                                                          \
    }                                                                            \
    _Pragma("unroll")                                                            \
    for (int ks = 0; ks < 2; ++ks) {                                             \
      s8v pa = *(const s8v*)&pw[ll * 72 + ks * 32 + akg];                        \
      __builtin_amdgcn_s_setprio(1);                                             \
      _Pragma("unroll")                                                          \
      for (int dq = 0; dq < 4; ++dq) {                                           \
        s8v vf = *(const s8v*)&Vt[(ll + 16 * dq) * 72 + ks * 32 + akg];          \
        o[dq] = __builtin_amdgcn_mfma_f32_16x16x32_bf16(pa, vf, o[dq], 0, 0, 0); \
      }                                                                          \
      __builtin_amdgcn_s_setprio(0);                                             \
    }                                                                            \
    __syncthreads();                         /* drains vmcnt: stage(T+1) is old -> free */ \
    if ((T) < 15) {                                                              \
      vwrite(VCONS);                         /* Vt <- V(T+1) */                  \
      if ((T) < 14) {                                                            \
        stage((T) + 2 > 15 ? 0 : ((T) + 2) * 64, PAR);                           \
        VPROD = vload(((T) + 2) * 64);                                           \
      }                                                                          \
      asm volatile("s_waitcnt lgkmcnt(0)" ::: "memory");                         \
      __builtin_amdgcn_sched_barrier(0);                                         \
      __builtin_amdgcn_s_barrier();                                              \
    }                                                                            \
  }

  for (int t2 = 0; t2 < 16; t2 += 2) {
    ATTN_TILE(t2, 0, vv1, vv0);
    ATTN_TILE(t2 + 1, 1, vv0, vv1);
  }
#undef ATTN_TILE

  #pragma unroll
  for (int r = 0; r < 4; ++r) {
    float v = lsum[r];
    v += __shfl_xor(v, 1);
    v += __shfl_xor(v, 2);
    v += __shfl_xor(v, 4);
    v += __shfl_xor(v, 8);
    lsum[r] = 1.0f / v;
  }
  #pragma unroll
  for (int ds = 0; ds < 4; ++ds) {
    #pragma unroll
    for (int r = 0; r < 4; ++r) {
      AO[((size_t)b * 1024 + iw + rowg + r) * 1024 + h * 64 + ll + 16 * ds] =
          f2bf(o[ds][r] * lsum[r]);
    }
  }
}

// ---------------- launcher ----------------

extern "C" void kernel_launch(void* const* d_in, const int* in_sizes, int n_in,
                              void* d_out, int out_size, void* d_ws, size_t ws_size,
                              hipStream_t stream) {
  const float* x     = (const float*)d_in[0];
  const float* t_enc = (const float*)d_in[1];
  const float* WQ    = (const float*)d_in[2];
  const float* WK    = (const float*)d_in[3];
  const float* WV    = (const float*)d_in[4];
  const float* WO    = (const float*)d_in[5];
  const float* bO    = (const float*)d_in[6];
  const float* Wt    = (const float*)d_in[7];
  const float* bt    = (const float*)d_in[8];
  const float* p_mat = (const float*)d_in[9];
  const float* r_mat = (const float*)d_in[10];
  const float* alpha = (const float*)d_in[11];
  const float* beta  = (const float*)d_in[12];
  const float* gamma = (const float*)d_in[13];
  float* out = (float*)d_out;

  char* ws = (char*)d_ws;
  unsigned short* xb  = (unsigned short*)(ws + ((size_t)0 << 20));
  unsigned short* xlo = (unsigned short*)(ws + ((size_t)8 << 20));
  unsigned short* wb  = (unsigned short*)(ws + ((size_t)16 << 20));
  unsigned short* Qb  = (unsigned short*)(ws + ((size_t)24 << 20));
  unsigned short* Kb  = (unsigned short*)(ws + ((size_t)32 << 20));
  unsigned short* Vb  = (unsigned short*)(ws + ((size_t)40 << 20));
  unsigned short* AO  = (unsigned short*)(ws + ((size_t)48 << 20));
  float* q_vec  = (float*)(ws + ((size_t)56 << 20));
  float* r_vec  = q_vec + 1024;
  float* coords = r_vec + 1024;
  float* q_sca  = coords + 4096;

  hipMemsetAsync(q_vec, 0, 2048 * sizeof(float), stream);
  colsum_kernel<<<dim3(4, 32), 256, 0, stream>>>(p_mat, r_mat, q_vec, r_vec);
  coords_kernel<<<1024, 256, 0, stream>>>(t_enc, Wt, bt, q_vec, coords, q_sca);
  conv_all_kernel<<<32768, 256, 0, stream>>>(x, WQ, WK, WV, WO, xb, xlo, wb);
  gemm_qkv_kernel<<<dim3(24, 32), 256, 0, stream>>>(xb, wb, Qb, Kb, Vb);
  attn_kernel<<<512, 512, 0, stream>>>(Qb, Kb, Vb, xb, xlo, coords, q_sca,
                                       r_vec, alpha, beta, gamma, AO);
  gemm_out_kernel<<<dim3(8, 32), 256, 0, stream>>>(AO, wb + ((size_t)3 << 20), bO, out);
}

// Round 8
// 283.950 us; speedup vs baseline: 1.5501x; 1.0206x over previous
//
#include <hip/hip_runtime.h>
#include <cstdint>
#include <cstddef>

typedef __attribute__((ext_vector_type(8))) short s8v;
typedef __attribute__((ext_vector_type(4))) float f32x4;

__device__ __forceinline__ unsigned short f2bf(float f) {
  unsigned int u = __builtin_bit_cast(unsigned int, f);
  unsigned int r = (u + 0x7fffu + ((u >> 16) & 1u)) >> 16;
  return (unsigned short)r;
}
__device__ __forceinline__ float bf2f(unsigned short s) {
  unsigned int u = ((unsigned int)s) << 16;
  return __builtin_bit_cast(float, u);
}

__device__ __forceinline__ void gload16(const void* g, void* l) {
  __builtin_amdgcn_global_load_lds(
      (const __attribute__((address_space(1))) void*)g,
      (__attribute__((address_space(3))) void*)l, 16, 0, 0);
}

// ---------------- prep kernels ----------------

// parallel column-sum: grid (4, 32), atomicAdd into zeroed q_vec/r_vec
__global__ __launch_bounds__(256)
void colsum_kernel(const float* __restrict__ p_mat, const float* __restrict__ r_mat,
                   float* __restrict__ q_vec, float* __restrict__ r_vec) {
  int col = blockIdx.x * 256 + threadIdx.x;   // 0..1023
  int d0 = blockIdx.y * 32;
  float sp = 0.f, sr = 0.f;
  for (int d = d0; d < d0 + 32; ++d) {
    sp += p_mat[d * 1024 + col];
    sr += r_mat[d * 1024 + col];
  }
  atomicAdd(&q_vec[col], sp);
  atomicAdd(&r_vec[col], sr);
}

__global__ __launch_bounds__(256)
void coords_kernel(const float* __restrict__ t_enc, const float* __restrict__ Wt,
                   const float* __restrict__ bt, const float* __restrict__ q_vec,
                   float* __restrict__ coords, float* __restrict__ q_sca) {
  int item = blockIdx.x * 4 + (threadIdx.x >> 6);   // 0..4095 = b*1024 + l
  int lane = threadIdx.x & 63;
  float v = t_enc[(size_t)item * 64 + lane] * Wt[lane];
  v += __shfl_xor(v, 32);
  v += __shfl_xor(v, 16);
  v += __shfl_xor(v, 8);
  v += __shfl_xor(v, 4);
  v += __shfl_xor(v, 2);
  v += __shfl_xor(v, 1);
  if (lane == 0) {
    float z = v + bt[0];
    float tau = 1.0f / (1.0f + expf(-z));
    float c = tau * 1023.0f;
    coords[item] = c;
    float fi = floorf(c);
    int i = (int)fi;
    float t = c - fi;
    int im1 = i - 1; if (im1 < 0) im1 = 0; if (im1 > 1023) im1 = 1023;
    int i0 = i; if (i0 < 0) i0 = 0; if (i0 > 1023) i0 = 1023;
    int i1 = i + 1; if (i1 > 1023) i1 = 1023;
    int i2 = i + 2; if (i2 > 1023) i2 = 1023;
    float p0 = q_vec[im1], p1 = q_vec[i0], p2 = q_vec[i1], p3 = q_vec[i2];
    float t2 = t * t, t3 = t2 * t;
    q_sca[item] = 0.5f * (2.f * p1 + (-p0 + p2) * t +
                          (2.f * p0 - 5.f * p1 + 4.f * p2 - p3) * t2 +
                          (-p0 + 3.f * p1 - 3.f * p2 + p3) * t3);
  }
}

// merged convx + convw: blocks [0,16384) convert x -> hi/lo bf16; rest convert weights
__global__ __launch_bounds__(256)
void conv_all_kernel(const float* __restrict__ x,
                     const float* __restrict__ w0, const float* __restrict__ w1,
                     const float* __restrict__ w2, const float* __restrict__ w3,
                     unsigned short* __restrict__ xb, unsigned short* __restrict__ xlo,
                     unsigned short* __restrict__ wb) {
  int bx = blockIdx.x;
  if (bx < 16384) {
    int i = bx * 256 + threadIdx.x;
    float f = x[i];
    unsigned short h = f2bf(f);
    xb[i] = h;
    xlo[i] = f2bf(f - bf2f(h));
  } else {
    int i = (bx - 16384) * 256 + threadIdx.x;
    int sel = i >> 20;
    const float* w = (sel == 0) ? w0 : (sel == 1) ? w1 : (sel == 2) ? w2 : w3;
    wb[i] = f2bf(w[i & 0xFFFFF]);
  }
}

// ---------------- GEMM: QKV projections ----------------
// C = A(4096x1024) * B^T. grid (24, 32). 128x128 tile, BK=64, 4 waves.
// Double-buffered pipeline + T2 XOR-swizzle (pre-swizzled global source col,
// swizzled ds_read col) to kill the 16-way frag-read bank conflict.

__global__ __launch_bounds__(256, 2)
void gemm_qkv_kernel(const unsigned short* __restrict__ Abuf,
                     const unsigned short* __restrict__ Wb,
                     unsigned short* __restrict__ Qb,
                     unsigned short* __restrict__ Kb,
                     unsigned short* __restrict__ Vb) {
  __shared__ unsigned short As[2][128 * 64];
  __shared__ unsigned short Bs[2][128 * 64];
  const int tid = threadIdx.x, w = tid >> 6, l = tid & 63;
  const int sel = blockIdx.x >> 3;
  const int nb = (blockIdx.x & 7) * 128;
  const int m0 = blockIdx.y * 128;
  const unsigned short* Bbuf = Wb + ((size_t)sel << 20);
  const int wr = w >> 1, wc = w & 1;
  const int ll = l & 15, lg = l >> 4;
  const int cs = (((l & 7) ^ ((l >> 3) & 7)) * 8);   // inverse-swizzled source col

  const f32x4 zero4 = {0.f, 0.f, 0.f, 0.f};
  f32x4 acc[4][4];
  #pragma unroll
  for (int i = 0; i < 4; ++i) {
    #pragma unroll
    for (int j = 0; j < 4; ++j) acc[i][j] = zero4;
  }

  auto stage = [&](int kt, int buf) {
    #pragma unroll
    for (int q = 0; q < 4; ++q) {
      const int seg = w * 4 + q;
      const int row = seg * 8 + (l >> 3);
      const int col = kt * 64 + cs;
      gload16(Abuf + (size_t)(m0 + row) * 1024 + col, &As[buf][seg * 512 + l * 8]);
      gload16(Bbuf + (size_t)(nb + row) * 1024 + col, &Bs[buf][seg * 512 + l * 8]);
    }
  };

  stage(0, 0);
  for (int kt = 0; kt < 16; ++kt) {
    __syncthreads();                    // drains vmcnt: tile kt ready (staged last iter)
    if (kt < 15) stage(kt + 1, (kt + 1) & 1);
    const int bb = kt & 1;
    #pragma unroll
    for (int ks = 0; ks < 2; ++ks) {
      const int gsw = ((ks * 4 + lg) ^ (ll & 7)) * 8;   // swizzled col group
      s8v af[4], bf[4];
      #pragma unroll
      for (int mi = 0; mi < 4; ++mi)
        af[mi] = *(const s8v*)&As[bb][(wr * 64 + mi * 16 + ll) * 64 + gsw];
      #pragma unroll
      for (int ni = 0; ni < 4; ++ni)
        bf[ni] = *(const s8v*)&Bs[bb][(wc * 64 + ni * 16 + ll) * 64 + gsw];
      #pragma unroll
      for (int mi = 0; mi < 4; ++mi) {
        #pragma unroll
        for (int ni = 0; ni < 4; ++ni)
          acc[mi][ni] = __builtin_amdgcn_mfma_f32_16x16x32_bf16(af[mi], bf[ni], acc[mi][ni], 0, 0, 0);
      }
    }
  }

  // coalesced epilogue via LDS transpose: 4 chunks of 32 rows x 128 cols (pad 136)
  unsigned short* dst = (sel == 0) ? Qb : ((sel == 1) ? Kb : Vb);
  unsigned short* ch = &As[0][0];       // 32*136 = 4352 shorts
  const int err = tid >> 3;             // epilogue read row 0..31
  const int ecb = tid & 7;              // epilogue col block 0..7
  #pragma unroll
  for (int mi = 0; mi < 4; ++mi) {
    __syncthreads();
    #pragma unroll
    for (int ni = 0; ni < 4; ++ni) {
      #pragma unroll
      for (int r = 0; r < 4; ++r)
        ch[(wr * 16 + lg * 4 + r) * 136 + wc * 64 + ni * 16 + ll] = f2bf(acc[mi][ni][r]);
    }
    __syncthreads();
    int m = m0 + (err >> 4) * 64 + mi * 16 + (err & 15);
    int ncol = nb + ecb * 16;
    int bb2 = m >> 10, lr = m & 1023, hh = ncol >> 6, dd = ncol & 63;
    unsigned short* gp = &dst[(((size_t)bb2 * 16 + hh) * 1024 + lr) * 64 + dd];
    *(s8v*)(gp)     = *(const s8v*)&ch[err * 136 + ecb * 16];
    *(s8v*)(gp + 8) = *(const s8v*)&ch[err * 136 + ecb * 16 + 8];
  }
}

// ---------------- GEMM: output projection ----------------
// out(4096x1024) = AO(4096x1024 bf16) * WO^T + bO ; grid (8, 32); dbuf + swizzle.

__global__ __launch_bounds__(256, 2)
void gemm_out_kernel(const unsigned short* __restrict__ Abuf,
                     const unsigned short* __restrict__ Bbuf,
                     const float* __restrict__ bO,
                     float* __restrict__ out) {
  __shared__ unsigned short As[2][128 * 64];
  __shared__ unsigned short Bs[2][128 * 64];
  const int tid = threadIdx.x, w = tid >> 6, l = tid & 63;
  const int nb = blockIdx.x * 128;
  const int m0 = blockIdx.y * 128;
  const int wr = w >> 1, wc = w & 1;
  const int ll = l & 15, lg = l >> 4;
  const int cs = (((l & 7) ^ ((l >> 3) & 7)) * 8);

  const f32x4 zero4 = {0.f, 0.f, 0.f, 0.f};
  f32x4 acc[4][4];
  #pragma unroll
  for (int i = 0; i < 4; ++i) {
    #pragma unroll
    for (int j = 0; j < 4; ++j) acc[i][j] = zero4;
  }

  auto stage = [&](int kt, int buf) {
    #pragma unroll
    for (int q = 0; q < 4; ++q) {
      const int seg = w * 4 + q;
      const int row = seg * 8 + (l >> 3);
      const int col = kt * 64 + cs;
      gload16(Abuf + (size_t)(m0 + row) * 1024 + col, &As[buf][seg * 512 + l * 8]);
      gload16(Bbuf + (size_t)(nb + row) * 1024 + col, &Bs[buf][seg * 512 + l * 8]);
    }
  };

  stage(0, 0);
  for (int kt = 0; kt < 16; ++kt) {
    __syncthreads();
    if (kt < 15) stage(kt + 1, (kt + 1) & 1);
    const int bb = kt & 1;
    #pragma unroll
    for (int ks = 0; ks < 2; ++ks) {
      const int gsw = ((ks * 4 + lg) ^ (ll & 7)) * 8;
      s8v af[4], bf[4];
      #pragma unroll
      for (int mi = 0; mi < 4; ++mi)
        af[mi] = *(const s8v*)&As[bb][(wr * 64 + mi * 16 + ll) * 64 + gsw];
      #pragma unroll
      for (int ni = 0; ni < 4; ++ni)
        bf[ni] = *(const s8v*)&Bs[bb][(wc * 64 + ni * 16 + ll) * 64 + gsw];
      #pragma unroll
      for (int mi = 0; mi < 4; ++mi) {
        #pragma unroll
        for (int ni = 0; ni < 4; ++ni)
          acc[mi][ni] = __builtin_amdgcn_mfma_f32_16x16x32_bf16(af[mi], bf[ni], acc[mi][ni], 0, 0, 0);
      }
    }
  }

  #pragma unroll
  for (int mi = 0; mi < 4; ++mi) {
    #pragma unroll
    for (int ni = 0; ni < 4; ++ni) {
      #pragma unroll
      for (int r = 0; r < 4; ++r) {
        int m = m0 + wr * 64 + mi * 16 + (l >> 4) * 4 + r;
        int ncol = nb + wc * 64 + ni * 16 + ll;
        out[(size_t)m * 1024 + ncol] = acc[mi][ni][r] + bO[ncol];
      }
    }
  }
}

// ---------------- fused attention ----------------
// 512 threads (8 waves), i-tile = 128 rows (wave w owns 16). grid: 512 blocks 1-D,
// XCD-swizzled. __launch_bounds__(512,2) => 128-VGPR budget, no spills.
// No s_setprio: 2-phase lockstep schedule -> T5 null-to-negative (measured r5).

__global__ __launch_bounds__(512, 2)
void attn_kernel(const unsigned short* __restrict__ Qb,
                 const unsigned short* __restrict__ Kb,
                 const unsigned short* __restrict__ Vb,
                 const unsigned short* __restrict__ xb,
                 const unsigned short* __restrict__ xlo,
                 const float* __restrict__ coords,
                 const float* __restrict__ q_sca,
                 const float* __restrict__ r_vec,
                 const float* __restrict__ alpha,
                 const float* __restrict__ beta,
                 const float* __restrict__ gamma,
                 unsigned short* __restrict__ AO) {
  __shared__ float r_s[1026];
  __shared__ unsigned short Ks[2][64 * 64];
  __shared__ unsigned short Ph[2][64 * 64];
  __shared__ unsigned short Pl[2][64 * 64];
  __shared__ unsigned short Vt[64 * 72];
  __shared__ unsigned short pbuf[8][16 * 72];

  const int tid = threadIdx.x;
  const int w = tid >> 6;
  const int l = tid & 63;
  const int gid = blockIdx.x;
  const int bh = (gid & 7) * 8 + ((gid >> 3) >> 3);   // XCD gid%8 owns 8 bh values
  const int xt = (gid >> 3) & 7;
  const int b = bh >> 4;
  const int h = bh & 15;
  const int iw = xt * 128 + w * 16;

  for (int t = tid; t < 1024; t += 512) r_s[t] = r_vec[t];
  if (tid < 2) r_s[1024 + tid] = r_vec[1023];

  const float INVLN2 = 1.4426950408889634f;
  const float a_h = alpha[h] * INVLN2, b_h = beta[h] * INVLN2, c_h = gamma[h] * INVLN2;
  const int lg = l >> 4;
  const int ll = l & 15;
  const int rowg = lg * 4;
  const int akg = lg * 8;

  float aqi[4], ci[4];
  #pragma unroll
  for (int r = 0; r < 4; ++r) {
    aqi[r] = fmaf(a_h, q_sca[b * 1024 + iw + rowg + r], c_h);
    ci[r] = coords[b * 1024 + iw + rowg + r];
  }

  s8v qf[2], pih[2], pil[2];
  {
    const unsigned short* qp = Qb + ((size_t)bh * 1024 + iw + ll) * 64 + akg;
    qf[0] = *(const s8v*)(qp);
    qf[1] = *(const s8v*)(qp + 32);
    const unsigned short* xp = xb + ((size_t)b * 1024 + iw + ll) * 1024 + h * 64 + akg;
    pih[0] = *(const s8v*)(xp);
    pih[1] = *(const s8v*)(xp + 32);
    const unsigned short* xq = xlo + ((size_t)b * 1024 + iw + ll) * 1024 + h * 64 + akg;
    pil[0] = *(const s8v*)(xq);
    pil[1] = *(const s8v*)(xq + 32);
  }

  const f32x4 zero4 = {0.f, 0.f, 0.f, 0.f};
  f32x4 o[4];
  #pragma unroll
  for (int ds = 0; ds < 4; ++ds) o[ds] = zero4;
  float mrow[4], lsum[4];
  #pragma unroll
  for (int r = 0; r < 4; ++r) { mrow[r] = -3.0e38f; lsum[r] = 0.f; }

  unsigned short* pw = pbuf[w];
  const int cs = (((l & 7) ^ ((l >> 3) & 7)) * 8);   // inverse-swizzled source col
  const int srow = l >> 3;

  auto stage = [&](int j0, int buf) {
    const int row = w * 8 + srow;
    gload16(Kb + ((size_t)bh * 1024 + j0 + row) * 64 + cs, &Ks[buf][w * 512 + l * 8]);
    gload16(xb + ((size_t)b * 1024 + j0 + row) * 1024 + h * 64 + cs, &Ph[buf][w * 512 + l * 8]);
    gload16(xlo + ((size_t)b * 1024 + j0 + row) * 1024 + h * 64 + cs, &Pl[buf][w * 512 + l * 8]);
  };
  auto vload = [&](int j0) -> s8v {
    return *(const s8v*)(Vb + ((size_t)bh * 1024 + j0 + l) * 64 + w * 8);
  };
  auto vwrite = [&](const s8v& vv) {
    #pragma unroll
    for (int e = 0; e < 8; ++e) Vt[(w * 8 + e) * 72 + l] = (unsigned short)vv[e];
  };

  // prologue: stage tiles 0,1 ; V(0),V(1) to regs; Vt <- V(0)
  stage(0, 0);
  s8v vv0 = vload(0);
  stage(64, 1);
  s8v vv1 = vload(64);
  vwrite(vv0);
  __syncthreads();

#define ATTN_TILE(T, PAR, VCONS, VPROD)                                          \
  {                                                                              \
    const int j0 = (T) * 64;                                                     \
    float cj[4], aqj[4];                                                         \
    _Pragma("unroll")                                                            \
    for (int s = 0; s < 4; ++s) {                                                \
      cj[s] = coords[b * 1024 + j0 + ll + 16 * s];                               \
      aqj[s] = a_h * q_sca[b * 1024 + j0 + ll + 16 * s];                         \
    }                                                                            \
    f32x4 aqk[4], app[4];                                                        \
    _Pragma("unroll")                                                            \
    for (int s = 0; s < 4; ++s) { aqk[s] = zero4; app[s] = zero4; }              \
    _Pragma("unroll")                                                            \
    for (int ks = 0; ks < 2; ++ks) {                                             \
      _Pragma("unroll")                                                          \
      for (int s = 0; s < 4; ++s) {                                              \
        const int rb = (ll + 16 * s) * 64 + (((ks * 4 + lg) ^ (ll & 7)) * 8);    \
        s8v kf = *(const s8v*)&Ks[PAR][rb];                                      \
        s8v hf = *(const s8v*)&Ph[PAR][rb];                                      \
        s8v lf = *(const s8v*)&Pl[PAR][rb];                                      \
        aqk[s] = __builtin_amdgcn_mfma_f32_16x16x32_bf16(qf[ks], kf, aqk[s], 0, 0, 0);   \
        app[s] = __builtin_amdgcn_mfma_f32_16x16x32_bf16(pih[ks], hf, app[s], 0, 0, 0);  \
        app[s] = __builtin_amdgcn_mfma_f32_16x16x32_bf16(pih[ks], lf, app[s], 0, 0, 0);  \
        app[s] = __builtin_amdgcn_mfma_f32_16x16x32_bf16(pil[ks], hf, app[s], 0, 0, 0);  \
      }                                                                          \
    }                                                                            \
    float tmax[4];                                                               \
    _Pragma("unroll")                                                            \
    for (int r = 0; r < 4; ++r) tmax[r] = -3.0e38f;                              \
    _Pragma("unroll")                                                            \
    for (int s = 0; s < 4; ++s) {                                                \
      _Pragma("unroll")                                                          \
      for (int r = 0; r < 4; ++r) {                                              \
        float delta = fabsf(ci[r] - cj[s]);                                      \
        int i0 = (int)delta;                                                     \
        float tt = delta - (float)i0;                                            \
        float r0 = r_s[i0];                                                      \
        float r1 = r_s[i0 + 1];                                                  \
        float rs = fmaf(tt, r1 - r0, r0);                                        \
        float S = fmaf(b_h, rs, aqi[r] + aqj[s]);                                \
        float v = fmaf(0.18033688f, aqk[s][r], S * app[s][r]);                   \
        app[s][r] = v;                                                           \
        tmax[r] = fmaxf(tmax[r], v);                                             \
      }                                                                          \
    }                                                                            \
    _Pragma("unroll")                                                            \
    for (int r = 0; r < 4; ++r) {                                                \
      float v = tmax[r];                                                         \
      v = fmaxf(v, __shfl_xor(v, 1));                                            \
      v = fmaxf(v, __shfl_xor(v, 2));                                            \
      v = fmaxf(v, __shfl_xor(v, 4));                                            \
      v = fmaxf(v, __shfl_xor(v, 8));                                            \
      float mn = fmaxf(mrow[r], v);                                              \
      float scale = exp2f(mrow[r] - mn);                                         \
      mrow[r] = mn;                                                              \
      lsum[r] *= scale;                                                          \
      o[0][r] *= scale; o[1][r] *= scale; o[2][r] *= scale; o[3][r] *= scale;    \
    }                                                                            \
    _Pragma("unroll")                                                            \
    for (int s = 0; s < 4; ++s) {                                                \
      _Pragma("unroll")                                                          \
      for (int r = 0; r < 4; ++r) {                                              \
        float e = exp2f(app[s][r] - mrow[r]);                                    \
        lsum[r] += e;                                                            \
        pw[(rowg + r) * 72 + ll + 16 * s] = f2bf(e);                             \
      }                                                                          \
    }                                                                            \
    _Pragma("unroll")                                                            \
    for (int ks = 0; ks < 2; ++ks) {                                             \
      s8v pa = *(const s8v*)&pw[ll * 72 + ks * 32 + akg];                        \
      _Pragma("unroll")                                                          \
      for (int dq = 0; dq < 4; ++dq) {                                           \
        s8v vf = *(const s8v*)&Vt[(ll + 16 * dq) * 72 + ks * 32 + akg];          \
        o[dq] = __builtin_amdgcn_mfma_f32_16x16x32_bf16(pa, vf, o[dq], 0, 0, 0); \
      }                                                                          \
    }                                                                            \
    __syncthreads();                         /* drains vmcnt: stage(T+1) is old -> free */ \
    if ((T) < 15) {                                                              \
      vwrite(VCONS);                         /* Vt <- V(T+1) */                  \
      if ((T) < 14) {                                                            \
        stage((T) + 2 > 15 ? 0 : ((T) + 2) * 64, PAR);                           \
        VPROD = vload(((T) + 2) * 64);                                           \
      }                                                                          \
      asm volatile("s_waitcnt lgkmcnt(0)" ::: "memory");                         \
      __builtin_amdgcn_sched_barrier(0);                                         \
      __builtin_amdgcn_s_barrier();                                              \
    }                                                                            \
  }

  for (int t2 = 0; t2 < 16; t2 += 2) {
    ATTN_TILE(t2, 0, vv1, vv0);
    ATTN_TILE(t2 + 1, 1, vv0, vv1);
  }
#undef ATTN_TILE

  #pragma unroll
  for (int r = 0; r < 4; ++r) {
    float v = lsum[r];
    v += __shfl_xor(v, 1);
    v += __shfl_xor(v, 2);
    v += __shfl_xor(v, 4);
    v += __shfl_xor(v, 8);
    lsum[r] = 1.0f / v;
  }
  #pragma unroll
  for (int ds = 0; ds < 4; ++ds) {
    #pragma unroll
    for (int r = 0; r < 4; ++r) {
      AO[((size_t)b * 1024 + iw + rowg + r) * 1024 + h * 64 + ll + 16 * ds] =
          f2bf(o[ds][r] * lsum[r]);
    }
  }
}

// ---------------- launcher ----------------

extern "C" void kernel_launch(void* const* d_in, const int* in_sizes, int n_in,
                              void* d_out, int out_size, void* d_ws, size_t ws_size,
                              hipStream_t stream) {
  const float* x     = (const float*)d_in[0];
  const float* t_enc = (const float*)d_in[1];
  const float* WQ    = (const float*)d_in[2];
  const float* WK    = (const float*)d_in[3];
  const float* WV    = (const float*)d_in[4];
  const float* WO    = (const float*)d_in[5];
  const float* bO    = (const float*)d_in[6];
  const float* Wt    = (const float*)d_in[7];
  const float* bt    = (const float*)d_in[8];
  const float* p_mat = (const float*)d_in[9];
  const float* r_mat = (const float*)d_in[10];
  const float* alpha = (const float*)d_in[11];
  const float* beta  = (const float*)d_in[12];
  const float* gamma = (const float*)d_in[13];
  float* out = (float*)d_out;

  char* ws = (char*)d_ws;
  unsigned short* xb  = (unsigned short*)(ws + ((size_t)0 << 20));
  unsigned short* xlo = (unsigned short*)(ws + ((size_t)8 << 20));
  unsigned short* wb  = (unsigned short*)(ws + ((size_t)16 << 20));
  unsigned short* Qb  = (unsigned short*)(ws + ((size_t)24 << 20));
  unsigned short* Kb  = (unsigned short*)(ws + ((size_t)32 << 20));
  unsigned short* Vb  = (unsigned short*)(ws + ((size_t)40 << 20));
  unsigned short* AO  = (unsigned short*)(ws + ((size_t)48 << 20));
  float* q_vec  = (float*)(ws + ((size_t)56 << 20));
  float* r_vec  = q_vec + 1024;
  float* coords = r_vec + 1024;
  float* q_sca  = coords + 4096;

  hipMemsetAsync(q_vec, 0, 2048 * sizeof(float), stream);
  colsum_kernel<<<dim3(4, 32), 256, 0, stream>>>(p_mat, r_mat, q_vec, r_vec);
  coords_kernel<<<1024, 256, 0, stream>>>(t_enc, Wt, bt, q_vec, coords, q_sca);
  conv_all_kernel<<<32768, 256, 0, stream>>>(x, WQ, WK, WV, WO, xb, xlo, wb);
  gemm_qkv_kernel<<<dim3(24, 32), 256, 0, stream>>>(xb, wb, Qb, Kb, Vb);
  attn_kernel<<<512, 512, 0, stream>>>(Qb, Kb, Vb, xb, xlo, coords, q_sca,
                                       r_vec, alpha, beta, gamma, AO);
  gemm_out_kernel<<<dim3(8, 32), 256, 0, stream>>>(AO, wb + ((size_t)3 << 20), bO, out);
}

// Round 9
// 267.690 us; speedup vs baseline: 1.6443x; 1.0607x over previous
//
#include <hip/hip_runtime.h>
#include <cstdint>
#include <cstddef>

typedef __attribute__((ext_vector_type(8))) short s8v;
typedef __attribute__((ext_vector_type(4))) float f32x4;

__device__ __forceinline__ unsigned short f2bf(float f) {
  unsigned int u = __builtin_bit_cast(unsigned int, f);
  unsigned int r = (u + 0x7fffu + ((u >> 16) & 1u)) >> 16;
  return (unsigned short)r;
}
__device__ __forceinline__ float bf2f(unsigned short s) {
  unsigned int u = ((unsigned int)s) << 16;
  return __builtin_bit_cast(float, u);
}

__device__ __forceinline__ void gload16(const void* g, void* l) {
  __builtin_amdgcn_global_load_lds(
      (const __attribute__((address_space(1))) void*)g,
      (__attribute__((address_space(3))) void*)l, 16, 0, 0);
}

// ---------------- prep kernels ----------------

// parallel column-sum: grid (4, 32), atomicAdd into zeroed q_vec/r_vec
__global__ __launch_bounds__(256)
void colsum_kernel(const float* __restrict__ p_mat, const float* __restrict__ r_mat,
                   float* __restrict__ q_vec, float* __restrict__ r_vec) {
  int col = blockIdx.x * 256 + threadIdx.x;   // 0..1023
  int d0 = blockIdx.y * 32;
  float sp = 0.f, sr = 0.f;
  for (int d = d0; d < d0 + 32; ++d) {
    sp += p_mat[d * 1024 + col];
    sr += r_mat[d * 1024 + col];
  }
  atomicAdd(&q_vec[col], sp);
  atomicAdd(&r_vec[col], sr);
}

__global__ __launch_bounds__(256)
void coords_kernel(const float* __restrict__ t_enc, const float* __restrict__ Wt,
                   const float* __restrict__ bt, const float* __restrict__ q_vec,
                   float* __restrict__ coords, float* __restrict__ q_sca) {
  int item = blockIdx.x * 4 + (threadIdx.x >> 6);   // 0..4095 = b*1024 + l
  int lane = threadIdx.x & 63;
  float v = t_enc[(size_t)item * 64 + lane] * Wt[lane];
  v += __shfl_xor(v, 32);
  v += __shfl_xor(v, 16);
  v += __shfl_xor(v, 8);
  v += __shfl_xor(v, 4);
  v += __shfl_xor(v, 2);
  v += __shfl_xor(v, 1);
  if (lane == 0) {
    float z = v + bt[0];
    float tau = 1.0f / (1.0f + expf(-z));
    float c = tau * 1023.0f;
    coords[item] = c;
    float fi = floorf(c);
    int i = (int)fi;
    float t = c - fi;
    int im1 = i - 1; if (im1 < 0) im1 = 0; if (im1 > 1023) im1 = 1023;
    int i0 = i; if (i0 < 0) i0 = 0; if (i0 > 1023) i0 = 1023;
    int i1 = i + 1; if (i1 > 1023) i1 = 1023;
    int i2 = i + 2; if (i2 > 1023) i2 = 1023;
    float p0 = q_vec[im1], p1 = q_vec[i0], p2 = q_vec[i1], p3 = q_vec[i2];
    float t2 = t * t, t3 = t2 * t;
    q_sca[item] = 0.5f * (2.f * p1 + (-p0 + p2) * t +
                          (2.f * p0 - 5.f * p1 + 4.f * p2 - p3) * t2 +
                          (-p0 + 3.f * p1 - 3.f * p2 + p3) * t3);
  }
}

// merged conv, 8 elems/thread (G13): blocks [0,2048) = x -> hi/lo bf16; rest = weights
__global__ __launch_bounds__(256)
void conv_all_kernel(const float* __restrict__ x,
                     const float* __restrict__ w0, const float* __restrict__ w1,
                     const float* __restrict__ w2, const float* __restrict__ w3,
                     unsigned short* __restrict__ xb, unsigned short* __restrict__ xlo,
                     unsigned short* __restrict__ wb) {
  int bx = blockIdx.x;
  if (bx < 2048) {
    size_t i8 = ((size_t)bx * 256 + threadIdx.x) * 8;
    float4 a = *(const float4*)(x + i8);
    float4 b = *(const float4*)(x + i8 + 4);
    float v[8] = {a.x, a.y, a.z, a.w, b.x, b.y, b.z, b.w};
    s8v h, lo;
    #pragma unroll
    for (int j = 0; j < 8; ++j) {
      unsigned short hh = f2bf(v[j]);
      h[j] = (short)hh;
      lo[j] = (short)f2bf(v[j] - bf2f(hh));
    }
    *(s8v*)(xb + i8) = h;
    *(s8v*)(xlo + i8) = lo;
  } else {
    size_t i8 = ((size_t)(bx - 2048) * 256 + threadIdx.x) * 8;
    int sel = (int)(i8 >> 20);
    const float* w = (sel == 0) ? w0 : (sel == 1) ? w1 : (sel == 2) ? w2 : w3;
    size_t off = i8 & 0xFFFFF;
    float4 a = *(const float4*)(w + off);
    float4 b = *(const float4*)(w + off + 4);
    float v[8] = {a.x, a.y, a.z, a.w, b.x, b.y, b.z, b.w};
    s8v h;
    #pragma unroll
    for (int j = 0; j < 8; ++j) h[j] = (short)f2bf(v[j]);
    *(s8v*)(wb + i8) = h;
  }
}

// ---------------- GEMM: QKV projections ----------------
// C = A(4096x1024) * B^T. grid (24, 32). 128x128 tile, BK=64, 4 waves.
// Double-buffered pipeline + T2 XOR-swizzle (both-sides, rule 21).

__global__ __launch_bounds__(256, 2)
void gemm_qkv_kernel(const unsigned short* __restrict__ Abuf,
                     const unsigned short* __restrict__ Wb,
                     unsigned short* __restrict__ Qb,
                     unsigned short* __restrict__ Kb,
                     unsigned short* __restrict__ Vb) {
  __shared__ unsigned short As[2][128 * 64];
  __shared__ unsigned short Bs[2][128 * 64];
  const int tid = threadIdx.x, w = tid >> 6, l = tid & 63;
  const int sel = blockIdx.x >> 3;
  const int nb = (blockIdx.x & 7) * 128;
  const int m0 = blockIdx.y * 128;
  const unsigned short* Bbuf = Wb + ((size_t)sel << 20);
  const int wr = w >> 1, wc = w & 1;
  const int ll = l & 15, lg = l >> 4;
  const int cs = (((l & 7) ^ ((l >> 3) & 7)) * 8);   // inverse-swizzled source col

  const f32x4 zero4 = {0.f, 0.f, 0.f, 0.f};
  f32x4 acc[4][4];
  #pragma unroll
  for (int i = 0; i < 4; ++i) {
    #pragma unroll
    for (int j = 0; j < 4; ++j) acc[i][j] = zero4;
  }

  auto stage = [&](int kt, int buf) {
    #pragma unroll
    for (int q = 0; q < 4; ++q) {
      const int seg = w * 4 + q;
      const int row = seg * 8 + (l >> 3);
      const int col = kt * 64 + cs;
      gload16(Abuf + (size_t)(m0 + row) * 1024 + col, &As[buf][seg * 512 + l * 8]);
      gload16(Bbuf + (size_t)(nb + row) * 1024 + col, &Bs[buf][seg * 512 + l * 8]);
    }
  };

  stage(0, 0);
  for (int kt = 0; kt < 16; ++kt) {
    __syncthreads();                    // drains vmcnt: tile kt ready (staged last iter)
    if (kt < 15) stage(kt + 1, (kt + 1) & 1);
    const int bb = kt & 1;
    #pragma unroll
    for (int ks = 0; ks < 2; ++ks) {
      const int gsw = ((ks * 4 + lg) ^ (ll & 7)) * 8;   // swizzled col group
      s8v af[4], bf[4];
      #pragma unroll
      for (int mi = 0; mi < 4; ++mi)
        af[mi] = *(const s8v*)&As[bb][(wr * 64 + mi * 16 + ll) * 64 + gsw];
      #pragma unroll
      for (int ni = 0; ni < 4; ++ni)
        bf[ni] = *(const s8v*)&Bs[bb][(wc * 64 + ni * 16 + ll) * 64 + gsw];
      #pragma unroll
      for (int mi = 0; mi < 4; ++mi) {
        #pragma unroll
        for (int ni = 0; ni < 4; ++ni)
          acc[mi][ni] = __builtin_amdgcn_mfma_f32_16x16x32_bf16(af[mi], bf[ni], acc[mi][ni], 0, 0, 0);
      }
    }
  }

  // coalesced epilogue via LDS transpose: 4 chunks of 32 rows x 128 cols (pad 136)
  unsigned short* dst = (sel == 0) ? Qb : ((sel == 1) ? Kb : Vb);
  unsigned short* ch = &As[0][0];       // 32*136 = 4352 shorts
  const int err = tid >> 3;             // epilogue read row 0..31
  const int ecb = tid & 7;              // epilogue col block 0..7
  #pragma unroll
  for (int mi = 0; mi < 4; ++mi) {
    __syncthreads();
    #pragma unroll
    for (int ni = 0; ni < 4; ++ni) {
      #pragma unroll
      for (int r = 0; r < 4; ++r)
        ch[(wr * 16 + lg * 4 + r) * 136 + wc * 64 + ni * 16 + ll] = f2bf(acc[mi][ni][r]);
    }
    __syncthreads();
    int m = m0 + (err >> 4) * 64 + mi * 16 + (err & 15);
    int ncol = nb + ecb * 16;
    int bb2 = m >> 10, lr = m & 1023, hh = ncol >> 6, dd = ncol & 63;
    unsigned short* gp = &dst[(((size_t)bb2 * 16 + hh) * 1024 + lr) * 64 + dd];
    *(s8v*)(gp)     = *(const s8v*)&ch[err * 136 + ecb * 16];
    *(s8v*)(gp + 8) = *(const s8v*)&ch[err * 136 + ecb * 16 + 8];
  }
}

// ---------------- GEMM: output projection ----------------

__global__ __launch_bounds__(256, 2)
void gemm_out_kernel(const unsigned short* __restrict__ Abuf,
                     const unsigned short* __restrict__ Bbuf,
                     const float* __restrict__ bO,
                     float* __restrict__ out) {
  __shared__ unsigned short As[2][128 * 64];
  __shared__ unsigned short Bs[2][128 * 64];
  const int tid = threadIdx.x, w = tid >> 6, l = tid & 63;
  const int nb = blockIdx.x * 128;
  const int m0 = blockIdx.y * 128;
  const int wr = w >> 1, wc = w & 1;
  const int ll = l & 15, lg = l >> 4;
  const int cs = (((l & 7) ^ ((l >> 3) & 7)) * 8);

  const f32x4 zero4 = {0.f, 0.f, 0.f, 0.f};
  f32x4 acc[4][4];
  #pragma unroll
  for (int i = 0; i < 4; ++i) {
    #pragma unroll
    for (int j = 0; j < 4; ++j) acc[i][j] = zero4;
  }

  auto stage = [&](int kt, int buf) {
    #pragma unroll
    for (int q = 0; q < 4; ++q) {
      const int seg = w * 4 + q;
      const int row = seg * 8 + (l >> 3);
      const int col = kt * 64 + cs;
      gload16(Abuf + (size_t)(m0 + row) * 1024 + col, &As[buf][seg * 512 + l * 8]);
      gload16(Bbuf + (size_t)(nb + row) * 1024 + col, &Bs[buf][seg * 512 + l * 8]);
    }
  };

  stage(0, 0);
  for (int kt = 0; kt < 16; ++kt) {
    __syncthreads();
    if (kt < 15) stage(kt + 1, (kt + 1) & 1);
    const int bb = kt & 1;
    #pragma unroll
    for (int ks = 0; ks < 2; ++ks) {
      const int gsw = ((ks * 4 + lg) ^ (ll & 7)) * 8;
      s8v af[4], bf[4];
      #pragma unroll
      for (int mi = 0; mi < 4; ++mi)
        af[mi] = *(const s8v*)&As[bb][(wr * 64 + mi * 16 + ll) * 64 + gsw];
      #pragma unroll
      for (int ni = 0; ni < 4; ++ni)
        bf[ni] = *(const s8v*)&Bs[bb][(wc * 64 + ni * 16 + ll) * 64 + gsw];
      #pragma unroll
      for (int mi = 0; mi < 4; ++mi) {
        #pragma unroll
        for (int ni = 0; ni < 4; ++ni)
          acc[mi][ni] = __builtin_amdgcn_mfma_f32_16x16x32_bf16(af[mi], bf[ni], acc[mi][ni], 0, 0, 0);
      }
    }
  }

  #pragma unroll
  for (int mi = 0; mi < 4; ++mi) {
    #pragma unroll
    for (int ni = 0; ni < 4; ++ni) {
      #pragma unroll
      for (int r = 0; r < 4; ++r) {
        int m = m0 + wr * 64 + mi * 16 + (l >> 4) * 4 + r;
        int ncol = nb + wc * 64 + ni * 16 + ll;
        out[(size_t)m * 1024 + ncol] = acc[mi][ni][r] + bO[ncol];
      }
    }
  }
}

// ---------------- fused attention ----------------
// 512 threads (8 waves), i-tile = 128 rows. grid: 512 blocks 1-D, XCD-swizzled.
// (512,2) => 128-VGPR budget. rp_s float2 pair table (1 ds_read_b64 per lerp);
// pbuf/Vt stride 64 + XOR group-swizzle. LDS = 81920 B exactly (2 blocks/CU).

__global__ __launch_bounds__(512, 2)
void attn_kernel(const unsigned short* __restrict__ Qb,
                 const unsigned short* __restrict__ Kb,
                 const unsigned short* __restrict__ Vb,
                 const unsigned short* __restrict__ xb,
                 const unsigned short* __restrict__ xlo,
                 const float* __restrict__ coords,
                 const float* __restrict__ q_sca,
                 const float* __restrict__ r_vec,
                 const float* __restrict__ alpha,
                 const float* __restrict__ beta,
                 const float* __restrict__ gamma,
                 unsigned short* __restrict__ AO) {
  __shared__ float2 rp_s[1024];
  __shared__ unsigned short Ks[2][64 * 64];
  __shared__ unsigned short Ph[2][64 * 64];
  __shared__ unsigned short Pl[2][64 * 64];
  __shared__ unsigned short Vt[64 * 64];
  __shared__ unsigned short pbuf[8][16 * 64];

  const int tid = threadIdx.x;
  const int w = tid >> 6;
  const int l = tid & 63;
  const int gid = blockIdx.x;
  const int bh = (gid & 7) * 8 + ((gid >> 3) >> 3);   // XCD gid%8 owns 8 bh values
  const int xt = (gid >> 3) & 7;
  const int b = bh >> 4;
  const int h = bh & 15;
  const int iw = xt * 128 + w * 16;

  for (int t = tid; t < 1024; t += 512) {
    float r0 = r_vec[t];
    float r1 = r_vec[t < 1023 ? t + 1 : 1023];
    rp_s[t] = make_float2(r0, r1);
  }

  const float INVLN2 = 1.4426950408889634f;
  const float a_h = alpha[h] * INVLN2, b_h = beta[h] * INVLN2, c_h = gamma[h] * INVLN2;
  const int lg = l >> 4;
  const int ll = l & 15;
  const int rowg = lg * 4;
  const int akg = lg * 8;

  float aqi[4], ci[4];
  #pragma unroll
  for (int r = 0; r < 4; ++r) {
    aqi[r] = fmaf(a_h, q_sca[b * 1024 + iw + rowg + r], c_h);
    ci[r] = coords[b * 1024 + iw + rowg + r];
  }

  s8v qf[2], pih[2], pil[2];
  {
    const unsigned short* qp = Qb + ((size_t)bh * 1024 + iw + ll) * 64 + akg;
    qf[0] = *(const s8v*)(qp);
    qf[1] = *(const s8v*)(qp + 32);
    const unsigned short* xp = xb + ((size_t)b * 1024 + iw + ll) * 1024 + h * 64 + akg;
    pih[0] = *(const s8v*)(xp);
    pih[1] = *(const s8v*)(xp + 32);
    const unsigned short* xq = xlo + ((size_t)b * 1024 + iw + ll) * 1024 + h * 64 + akg;
    pil[0] = *(const s8v*)(xq);
    pil[1] = *(const s8v*)(xq + 32);
  }

  const f32x4 zero4 = {0.f, 0.f, 0.f, 0.f};
  f32x4 o[4];
  #pragma unroll
  for (int ds = 0; ds < 4; ++ds) o[ds] = zero4;
  float mrow[4], lsum[4];
  #pragma unroll
  for (int r = 0; r < 4; ++r) { mrow[r] = -3.0e38f; lsum[r] = 0.f; }

  unsigned short* pw = pbuf[w];
  const int cs = (((l & 7) ^ ((l >> 3) & 7)) * 8);   // inverse-swizzled source col
  const int srow = l >> 3;

  auto stage = [&](int j0, int buf) {
    const int row = w * 8 + srow;
    gload16(Kb + ((size_t)bh * 1024 + j0 + row) * 64 + cs, &Ks[buf][w * 512 + l * 8]);
    gload16(xb + ((size_t)b * 1024 + j0 + row) * 1024 + h * 64 + cs, &Ph[buf][w * 512 + l * 8]);
    gload16(xlo + ((size_t)b * 1024 + j0 + row) * 1024 + h * 64 + cs, &Pl[buf][w * 512 + l * 8]);
  };
  auto vload = [&](int j0) -> s8v {
    return *(const s8v*)(Vb + ((size_t)bh * 1024 + j0 + l) * 64 + w * 8);
  };
  auto vwrite = [&](const s8v& vv) {
    #pragma unroll
    for (int e = 0; e < 8; ++e) {
      const int row = w * 8 + e;
      Vt[row * 64 + (((l >> 3) ^ (row & 7)) * 8) + (l & 7)] = (unsigned short)vv[e];
    }
  };

  // prologue: stage tiles 0,1 ; V(0),V(1) to regs; Vt <- V(0)
  stage(0, 0);
  s8v vv0 = vload(0);
  stage(64, 1);
  s8v vv1 = vload(64);
  vwrite(vv0);
  __syncthreads();

#define ATTN_TILE(T, PAR, VCONS, VPROD)                                          \
  {                                                                              \
    const int j0 = (T) * 64;                                                     \
    float cj[4], aqj[4];                                                         \
    _Pragma("unroll")                                                            \
    for (int s = 0; s < 4; ++s) {                                                \
      cj[s] = coords[b * 1024 + j0 + ll + 16 * s];                               \
      aqj[s] = a_h * q_sca[b * 1024 + j0 + ll + 16 * s];                         \
    }                                                                            \
    f32x4 aqk[4], app[4];                                                        \
    _Pragma("unroll")                                                            \
    for (int s = 0; s < 4; ++s) { aqk[s] = zero4; app[s] = zero4; }              \
    _Pragma("unroll")                                                            \
    for (int ks = 0; ks < 2; ++ks) {                                             \
      _Pragma("unroll")                                                          \
      for (int s = 0; s < 4; ++s) {                                              \
        const int rb = (ll + 16 * s) * 64 + (((ks * 4 + lg) ^ (ll & 7)) * 8);    \
        s8v kf = *(const s8v*)&Ks[PAR][rb];                                      \
        s8v hf = *(const s8v*)&Ph[PAR][rb];                                      \
        s8v lf = *(const s8v*)&Pl[PAR][rb];                                      \
        aqk[s] = __builtin_amdgcn_mfma_f32_16x16x32_bf16(qf[ks], kf, aqk[s], 0, 0, 0);   \
        app[s] = __builtin_amdgcn_mfma_f32_16x16x32_bf16(pih[ks], hf, app[s], 0, 0, 0);  \
        app[s] = __builtin_amdgcn_mfma_f32_16x16x32_bf16(pih[ks], lf, app[s], 0, 0, 0);  \
        app[s] = __builtin_amdgcn_mfma_f32_16x16x32_bf16(pil[ks], hf, app[s], 0, 0, 0);  \
      }                                                                          \
    }                                                                            \
    float tmax[4];                                                               \
    _Pragma("unroll")                                                            \
    for (int r = 0; r < 4; ++r) tmax[r] = -3.0e38f;                              \
    _Pragma("unroll")                                                            \
    for (int s = 0; s < 4; ++s) {                                                \
      _Pragma("unroll")                                                          \
      for (int r = 0; r < 4; ++r) {                                              \
        float delta = fabsf(ci[r] - cj[s]);                                      \
        int i0 = (int)delta;                                                     \
        float tt = delta - (float)i0;                                            \
        float2 rr = rp_s[i0];                                                    \
        float rs = fmaf(tt, rr.y - rr.x, rr.x);                                  \
        float S = fmaf(b_h, rs, aqi[r] + aqj[s]);                                \
        float v = fmaf(0.18033688f, aqk[s][r], S * app[s][r]);                   \
        app[s][r] = v;                                                           \
        tmax[r] = fmaxf(tmax[r], v);                                             \
      }                                                                          \
    }                                                                            \
    _Pragma("unroll")                                                            \
    for (int r = 0; r < 4; ++r) {                                                \
      float v = tmax[r];                                                         \
      v = fmaxf(v, __shfl_xor(v, 1));                                            \
      v = fmaxf(v, __shfl_xor(v, 2));                                            \
      v = fmaxf(v, __shfl_xor(v, 4));                                            \
      v = fmaxf(v, __shfl_xor(v, 8));                                            \
      float mn = fmaxf(mrow[r], v);                                              \
      float scale = exp2f(mrow[r] - mn);                                         \
      mrow[r] = mn;                                                              \
      lsum[r] *= scale;                                                          \
      o[0][r] *= scale; o[1][r] *= scale; o[2][r] *= scale; o[3][r] *= scale;    \
    }                                                                            \
    _Pragma("unroll")                                                            \
    for (int s = 0; s < 4; ++s) {                                                \
      const int pg = ((2 * s + (ll >> 3)));                                      \
      _Pragma("unroll")                                                          \
      for (int r = 0; r < 4; ++r) {                                              \
        float e = exp2f(app[s][r] - mrow[r]);                                    \
        lsum[r] += e;                                                            \
        const int row = rowg + r;                                                \
        pw[row * 64 + ((pg ^ (row & 7)) * 8) + (ll & 7)] =                       \
            (unsigned short)(__builtin_bit_cast(unsigned int, e) >> 16);         \
      }                                                                          \
    }                                                                            \
    _Pragma("unroll")                                                            \
    for (int ks = 0; ks < 2; ++ks) {                                             \
      s8v pa = *(const s8v*)&pw[ll * 64 + (((ks * 4 + lg) ^ (ll & 7)) * 8)];     \
      _Pragma("unroll")                                                          \
      for (int dq = 0; dq < 4; ++dq) {                                           \
        const int vrow = ll + 16 * dq;                                           \
        s8v vf = *(const s8v*)&Vt[vrow * 64 + (((ks * 4 + lg) ^ (ll & 7)) * 8)]; \
        o[dq] = __builtin_amdgcn_mfma_f32_16x16x32_bf16(pa, vf, o[dq], 0, 0, 0); \
      }                                                                          \
    }                                                                            \
    __syncthreads();                         /* drains vmcnt: stage(T+1) is old -> free */ \
    if ((T) < 15) {                                                              \
      vwrite(VCONS);                         /* Vt <- V(T+1) */                  \
      if ((T) < 14) {                                                            \
        stage((T) + 2 > 15 ? 0 : ((T) + 2) * 64, PAR);                           \
        VPROD = vload(((T) + 2) * 64);                                           \
      }                                                                          \
      asm volatile("s_waitcnt lgkmcnt(0)" ::: "memory");                         \
      __builtin_amdgcn_sched_barrier(0);                                         \
      __builtin_amdgcn_s_barrier();                                              \
    }                                                                            \
  }

  for (int t2 = 0; t2 < 16; t2 += 2) {
    ATTN_TILE(t2, 0, vv1, vv0);
    ATTN_TILE(t2 + 1, 1, vv0, vv1);
  }
#undef ATTN_TILE

  #pragma unroll
  for (int r = 0; r < 4; ++r) {
    float v = lsum[r];
    v += __shfl_xor(v, 1);
    v += __shfl_xor(v, 2);
    v += __shfl_xor(v, 4);
    v += __shfl_xor(v, 8);
    lsum[r] = 1.0f / v;
  }
  #pragma unroll
  for (int ds = 0; ds < 4; ++ds) {
    #pragma unroll
    for (int r = 0; r < 4; ++r) {
      AO[((size_t)b * 1024 + iw + rowg + r) * 1024 + h * 64 + ll + 16 * ds] =
          f2bf(o[ds][r] * lsum[r]);
    }
  }
}

// ---------------- launcher ----------------

extern "C" void kernel_launch(void* const* d_in, const int* in_sizes, int n_in,
                              void* d_out, int out_size, void* d_ws, size_t ws_size,
                              hipStream_t stream) {
  const float* x     = (const float*)d_in[0];
  const float* t_enc = (const float*)d_in[1];
  const float* WQ    = (const float*)d_in[2];
  const float* WK    = (const float*)d_in[3];
  const float* WV    = (const float*)d_in[4];
  const float* WO    = (const float*)d_in[5];
  const float* bO    = (const float*)d_in[6];
  const float* Wt    = (const float*)d_in[7];
  const float* bt    = (const float*)d_in[8];
  const float* p_mat = (const float*)d_in[9];
  const float* r_mat = (const float*)d_in[10];
  const float* alpha = (const float*)d_in[11];
  const float* beta  = (const float*)d_in[12];
  const float* gamma = (const float*)d_in[13];
  float* out = (float*)d_out;

  char* ws = (char*)d_ws;
  unsigned short* xb  = (unsigned short*)(ws + ((size_t)0 << 20));
  unsigned short* xlo = (unsigned short*)(ws + ((size_t)8 << 20));
  unsigned short* wb  = (unsigned short*)(ws + ((size_t)16 << 20));
  unsigned short* Qb  = (unsigned short*)(ws + ((size_t)24 << 20));
  unsigned short* Kb  = (unsigned short*)(ws + ((size_t)32 << 20));
  unsigned short* Vb  = (unsigned short*)(ws + ((size_t)40 << 20));
  unsigned short* AO  = (unsigned short*)(ws + ((size_t)48 << 20));
  float* q_vec  = (float*)(ws + ((size_t)56 << 20));
  float* r_vec  = q_vec + 1024;
  float* coords = r_vec + 1024;
  float* q_sca  = coords + 4096;

  hipMemsetAsync(q_vec, 0, 2048 * sizeof(float), stream);
  colsum_kernel<<<dim3(4, 32), 256, 0, stream>>>(p_mat, r_mat, q_vec, r_vec);
  coords_kernel<<<1024, 256, 0, stream>>>(t_enc, Wt, bt, q_vec, coords, q_sca);
  conv_all_kernel<<<4096, 256, 0, stream>>>(x, WQ, WK, WV, WO, xb, xlo, wb);
  gemm_qkv_kernel<<<dim3(24, 32), 256, 0, stream>>>(xb, wb, Qb, Kb, Vb);
  attn_kernel<<<512, 512, 0, stream>>>(Qb, Kb, Vb, xb, xlo, coords, q_sca,
                                       r_vec, alpha, beta, gamma, AO);
  gemm_out_kernel<<<dim3(8, 32), 256, 0, stream>>>(AO, wb + ((size_t)3 << 20), bO, out);
}